// Round 22
// baseline (521.173 us; speedup 1.0000x reference)
//
#include <hip/hip_runtime.h>
#include <hip/hip_bf16.h>
#include <math.h>

// Problem constants (fixed by setup_inputs)
#define BB 2
#define TT 1024
#define DD 2048
#define HH 16
#define DK 128
#define DV 128
#define NG 8
#define GG 16
#define SCALE_Q 0.08838834764831845f  // 128^-0.5

typedef __attribute__((ext_vector_type(8))) short bf16x8;
typedef __attribute__((ext_vector_type(4))) float f32x4;

#define MFMA16(a, b, c) __builtin_amdgcn_mfma_f32_16x16x32_bf16((a), (b), (c), 0, 0, 0)

// bf16 split helpers (RNE)
__device__ __forceinline__ unsigned short f2bf(float v) {
    unsigned u = __float_as_uint(v);
    return (unsigned short)((u + 0x7FFFu + ((u >> 16) & 1u)) >> 16);
}
__device__ __forceinline__ float bf2f(unsigned short h) {
    return __uint_as_float(((unsigned)h) << 16);
}
__device__ __forceinline__ void bsplit(float v, unsigned short& h, unsigned short& l) {
    h = f2bf(v);
    l = f2bf(v - bf2f(h));
}
__device__ __forceinline__ void split8arr(const float* v, bf16x8& hi, bf16x8& lo) {
#pragma unroll
    for (int j = 0; j < 8; ++j) {
        unsigned short h, l;
        bsplit(v[j], h, l);
        hi[j] = (short)h;
        lo[j] = (short)l;
    }
}
__device__ __forceinline__ bf16x8 zero8() {
    bf16x8 z;
#pragma unroll
    for (int i = 0; i < 8; ++i) z[i] = 0;
    return z;
}

// ---------------------------------------------------------------------------
// DPP wave64 sum (fallback recurrence only).
// ---------------------------------------------------------------------------
__device__ __forceinline__ float dpp_sum64(float x) {
    x += __int_as_float(__builtin_amdgcn_update_dpp(0, __float_as_int(x), 0x111, 0xf, 0xf, true));
    x += __int_as_float(__builtin_amdgcn_update_dpp(0, __float_as_int(x), 0x112, 0xf, 0xf, true));
    x += __int_as_float(__builtin_amdgcn_update_dpp(0, __float_as_int(x), 0x114, 0xf, 0xf, true));
    x += __int_as_float(__builtin_amdgcn_update_dpp(0, __float_as_int(x), 0x118, 0xf, 0xf, true));
    x += __int_as_float(__builtin_amdgcn_update_dpp(0, __float_as_int(x), 0x142, 0xa, 0xf, false));
    x += __int_as_float(__builtin_amdgcn_update_dpp(0, __float_as_int(x), 0x143, 0xc, 0xf, false));
    return x;
}
__device__ __forceinline__ float readlanef(float x, int l) {
    return __int_as_float(__builtin_amdgcn_readlane(__float_as_int(x), l));
}

// ---------------------------------------------------------------------------
// split: fp32 [n] -> bf16 hi/lo
// ---------------------------------------------------------------------------
__global__ void split_mat(const float* __restrict__ in, unsigned short* __restrict__ oh,
                          unsigned short* __restrict__ ol) {
    const int i0 = (blockIdx.x * 256 + threadIdx.x) * 16;
#pragma unroll
    for (int r = 0; r < 4; ++r) {
        const float4 v = *(const float4*)(in + i0 + r * 4);
        unsigned short h0, l0, h1, l1, h2, l2, h3, l3;
        bsplit(v.x, h0, l0); bsplit(v.y, h1, l1);
        bsplit(v.z, h2, l2); bsplit(v.w, h3, l3);
        short4 hh; hh.x = (short)h0; hh.y = (short)h1; hh.z = (short)h2; hh.w = (short)h3;
        short4 ll; ll.x = (short)l0; ll.y = (short)l1; ll.z = (short)l2; ll.w = (short)l3;
        *(short4*)(oh + i0 + r * 4) = hh;
        *(short4*)(ol + i0 + r * 4) = ll;
    }
}

// ---------------------------------------------------------------------------
// transpose + split: in fp32 [Kin][Nin] -> out bf16 hi/lo [Nin][Kin]
// ---------------------------------------------------------------------------
__device__ __forceinline__ void tsplit_body(const float* __restrict__ in,
                                            unsigned short* __restrict__ oh,
                                            unsigned short* __restrict__ ol,
                                            int Nin, int Kin, int bx, int by, int tid) {
    __shared__ float t[64][65];
    const int c4 = (tid & 15) * 4, r0 = tid >> 4;
#pragma unroll
    for (int rep = 0; rep < 4; ++rep) {
        const int r = r0 + rep * 16;
        const float4 v = *(const float4*)(in + (size_t)(by * 64 + r) * Nin + bx * 64 + c4);
        t[r][c4] = v.x; t[r][c4 + 1] = v.y; t[r][c4 + 2] = v.z; t[r][c4 + 3] = v.w;
    }
    __syncthreads();
#pragma unroll
    for (int rep = 0; rep < 4; ++rep) {
        const int n = r0 + rep * 16;
        short4 hh, ll;
        unsigned short h, l;
        bsplit(t[c4 + 0][n], h, l); hh.x = (short)h; ll.x = (short)l;
        bsplit(t[c4 + 1][n], h, l); hh.y = (short)h; ll.y = (short)l;
        bsplit(t[c4 + 2][n], h, l); hh.z = (short)h; ll.z = (short)l;
        bsplit(t[c4 + 3][n], h, l); hh.w = (short)h; ll.w = (short)l;
        const size_t o = (size_t)(bx * 64 + n) * Kin + by * 64 + c4;
        *(short4*)(oh + o) = hh;
        *(short4*)(ol + o) = ll;
    }
}

__global__ void transpose_split(const float* __restrict__ in, unsigned short* __restrict__ oh,
                                unsigned short* __restrict__ ol, int Nin, int Kin) {
    tsplit_body(in, oh, ol, Nin, Kin, blockIdx.x, blockIdx.y, threadIdx.x);
}

struct TS4 { const float* in[4]; unsigned short* oh[4]; unsigned short* ol[4]; };
__global__ void transpose_split4(TS4 p) {
    const int z = blockIdx.z;
    tsplit_body(p.in[z], p.oh[z], p.ol[z], 2048, 2048, blockIdx.x, blockIdx.y, threadIdx.x);
}

// ---------------------------------------------------------------------------
// t-tile transpose x3: in [B][1024][2048] -> out tiled [bh][tblk][cl][8]
// ---------------------------------------------------------------------------
struct T3 { const float* in[3]; float* out[3]; };
__global__ void transpose_tile3(T3 p) {
    __shared__ float tl[8][128];
    const int z = blockIdx.y;
    const float* __restrict__ in = p.in[z];
    float* __restrict__ out = p.out[z];
    const int blk = blockIdx.x;
    const int bh = blk >> 7, tblk = blk & 127;
    const int b = bh >> 4, h = bh & 15;
    const int tid = threadIdx.x;

    const int tt = tid >> 5, c4 = (tid & 31) * 4;
    const float4 v = *(const float4*)(in + ((size_t)(b * 1024 + tblk * 8 + tt)) * 2048 + h * 128 + c4);
    tl[tt][c4] = v.x; tl[tt][c4 + 1] = v.y; tl[tt][c4 + 2] = v.z; tl[tt][c4 + 3] = v.w;
    __syncthreads();

    const int cl = tid >> 1, tj0 = (tid & 1) * 4;
    float4 w4;
    w4.x = tl[tj0 + 0][cl]; w4.y = tl[tj0 + 1][cl];
    w4.z = tl[tj0 + 2][cl]; w4.w = tl[tj0 + 3][cl];
    *(float4*)(out + ((size_t)blk * 128 + cl) * 8 + tj0) = w4;
}

// ---------------------------------------------------------------------------
// Split-precision bf16 MFMA GEMM, XCD-swizzled, NM = MFMA count (COMPILE-TIME):
//   NM=1: pure bf16 (Ah x Bh), stages 2 arrays  -- fused input projections
//   NM=2: split-2 (Ah x (Bh+Bl)), stages 3      -- output projection
//   NM=3: split-3 (hh+hl+lh), stages 4          -- Wf1 (decay-sensitive)
// mode 0: single output sel0, ldc 2048, nloc = bx*128   (out-proj, grid 16x16)
// mode 1: fused q/k/v/g, grid 64x16, sel = bx>>4        (input projections)
// mode 2: Wf1 single, grid 1x16, sel=4, nloc=0, ldc=128
// ---------------------------------------------------------------------------
struct GemmArgs {
    const unsigned short* Ah; const unsigned short* Al;
    const unsigned short* Bh[5]; const unsigned short* Bl[5];
    float* C[5];
};

#define AHI 0
#define ALO 8192
#define BHI 16384
#define BLO 24576

#define GL2LDS(g, s) __builtin_amdgcn_global_load_lds( \
    (const __attribute__((address_space(1))) void*)(g), \
    (__attribute__((address_space(3))) void*)(s), 16, 0, 0)

template <int NM>
__launch_bounds__(256, 3)
__global__ void gemm_split(GemmArgs p, int mode) {
    __shared__ __attribute__((aligned(16))) char lds[32768];
    const int tid = threadIdx.x;

    // XCD-aware bijective swizzle (gridDim.y == 16 for all launches)
    int bx, by;
    {
        const int gw = gridDim.x;
        const int lin = blockIdx.y * gw + blockIdx.x;
        const int per = (gw * 16) >> 3;
        const int swz = (lin & 7) * per + (lin >> 3);
        bx = swz >> 4;
        by = swz & 15;
    }

    int sel, nloc, ldc;
    if (mode == 1)      { sel = bx >> 4; nloc = (bx & 15) * 128; ldc = 2048; }
    else if (mode == 2) { sel = 4;       nloc = 0;               ldc = 128;  }
    else                { sel = 0;       nloc = bx * 128;        ldc = 2048; }

    const unsigned short* Asrc_h = p.Ah + (size_t)(by * 128) * 2048;
    const unsigned short* Asrc_l = p.Al + (size_t)(by * 128) * 2048;
    const unsigned short* Bsrc_h = p.Bh[sel] + (size_t)nloc * 2048;
    const unsigned short* Bsrc_l = p.Bl[sel] + (size_t)nloc * 2048;

    const int r0 = tid >> 2, ps0 = tid & 3;
    const int r1 = (tid + 256) >> 2, ps1 = tid & 3;
    const size_t ga0 = (size_t)r0 * 2048 + (size_t)((ps0 ^ ((r0 >> 1) & 3)) * 8);
    const size_t ga1 = (size_t)r1 * 2048 + (size_t)((ps1 ^ ((r1 >> 1) & 3)) * 8);
    const int lb0 = (tid & 192) * 16;
    const int lb1 = (256 + (tid & 192)) * 16;

    const int lane = tid & 63;
    const int l15 = lane & 15, kgrp = lane >> 4;
    const int w = tid >> 6, wm = w >> 1, wn = w & 1;
    const int swzf = kgrp ^ ((l15 >> 1) & 3);
    const int fro = l15 * 64 + swzf * 16;
    const int aoff = wm * 4096, boff = wn * 4096;

    f32x4 acc[4][4];
#pragma unroll
    for (int i = 0; i < 4; ++i)
#pragma unroll
        for (int j = 0; j < 4; ++j) acc[i][j] = (f32x4){0.f, 0.f, 0.f, 0.f};

    for (int k0 = 0; k0 < 2048; k0 += 32) {
        __syncthreads();
        GL2LDS(Asrc_h + k0 + ga0, lds + AHI + lb0);
        GL2LDS(Asrc_h + k0 + ga1, lds + AHI + lb1);
        if constexpr (NM >= 3) {
            GL2LDS(Asrc_l + k0 + ga0, lds + ALO + lb0);
            GL2LDS(Asrc_l + k0 + ga1, lds + ALO + lb1);
        }
        GL2LDS(Bsrc_h + k0 + ga0, lds + BHI + lb0);
        GL2LDS(Bsrc_h + k0 + ga1, lds + BHI + lb1);
        if constexpr (NM >= 2) {
            GL2LDS(Bsrc_l + k0 + ga0, lds + BLO + lb0);
            GL2LDS(Bsrc_l + k0 + ga1, lds + BLO + lb1);
        }
        __syncthreads();

        bf16x8 ah[4], bh4[4];
#pragma unroll
        for (int f = 0; f < 4; ++f) {
            ah[f]  = *(const bf16x8*)(lds + AHI + aoff + f * 1024 + fro);
            bh4[f] = *(const bf16x8*)(lds + BHI + boff + f * 1024 + fro);
        }
        if constexpr (NM == 1) {
#pragma unroll
            for (int i = 0; i < 4; ++i)
#pragma unroll
                for (int j = 0; j < 4; ++j)
                    acc[i][j] = MFMA16(ah[i], bh4[j], acc[i][j]);
        } else if constexpr (NM == 2) {
            bf16x8 bl4[4];
#pragma unroll
            for (int f = 0; f < 4; ++f)
                bl4[f] = *(const bf16x8*)(lds + BLO + boff + f * 1024 + fro);
#pragma unroll
            for (int i = 0; i < 4; ++i)
#pragma unroll
                for (int j = 0; j < 4; ++j) {
                    acc[i][j] = MFMA16(ah[i], bh4[j], acc[i][j]);
                    acc[i][j] = MFMA16(ah[i], bl4[j], acc[i][j]);
                }
        } else {
            bf16x8 bl4[4], al4[4];
#pragma unroll
            for (int f = 0; f < 4; ++f) {
                bl4[f] = *(const bf16x8*)(lds + BLO + boff + f * 1024 + fro);
                al4[f] = *(const bf16x8*)(lds + ALO + aoff + f * 1024 + fro);
            }
#pragma unroll
            for (int i = 0; i < 4; ++i)
#pragma unroll
                for (int j = 0; j < 4; ++j) {
                    acc[i][j] = MFMA16(ah[i],  bh4[j], acc[i][j]);
                    acc[i][j] = MFMA16(ah[i],  bl4[j], acc[i][j]);
                    acc[i][j] = MFMA16(al4[i], bh4[j], acc[i][j]);
                }
        }
    }

    float* cb = p.C[sel];
    const int m0 = by * 128 + wm * 64 + kgrp * 4;
    const int n0 = nloc + wn * 64 + l15;
#pragma unroll
    for (int i = 0; i < 4; ++i)
#pragma unroll
        for (int t = 0; t < 4; ++t) {
            float* cp = cb + (size_t)(m0 + i * 16 + t) * ldc + n0;
#pragma unroll
            for (int j = 0; j < 4; ++j) cp[j * 16] = acc[i][j][t];
        }
}

// ---------------------------------------------------------------------------
// Generic fp32 SGEMM (g1@Wf2 and fallback).
// ---------------------------------------------------------------------------
#define GBM 128
#define GBN 128
#define GBK 16

__launch_bounds__(256)
__global__ void sgemm128(const float* __restrict__ A, const float* __restrict__ B,
                         float* __restrict__ C, int M, int N, int K) {
    __shared__ float As[GBK][GBM + 4];
    __shared__ float Bs[GBK][GBN + 4];

    const int tid = threadIdx.x;
    const int bm = blockIdx.y * GBM;
    const int bn = blockIdx.x * GBN;

    const int arow = tid >> 2;
    const int acol = (tid & 3) << 2;
    const int brow = tid >> 5;
    const int bcol = (tid & 31) << 2;
    const int ty = tid >> 4;
    const int tx = tid & 15;

    float acc[8][8];
#pragma unroll
    for (int i = 0; i < 8; ++i)
#pragma unroll
        for (int j = 0; j < 8; ++j) acc[i][j] = 0.f;

    for (int k0 = 0; k0 < K; k0 += GBK) {
#pragma unroll
        for (int r = 0; r < 2; ++r) {
            const int m = arow + r * 64;
            const float4 av = *(const float4*)(A + (size_t)(bm + m) * K + k0 + acol);
            As[acol + 0][m] = av.x;
            As[acol + 1][m] = av.y;
            As[acol + 2][m] = av.z;
            As[acol + 3][m] = av.w;
        }
#pragma unroll
        for (int r = 0; r < 2; ++r) {
            const int kk = brow + r * 8;
            *(float4*)(&Bs[kk][bcol]) =
                *(const float4*)(B + (size_t)(k0 + kk) * N + bn + bcol);
        }
        __syncthreads();

#pragma unroll
        for (int kk = 0; kk < GBK; ++kk) {
            float a[8], bf[8];
#pragma unroll
            for (int i = 0; i < 8; ++i) a[i] = As[kk][ty * 8 + i];
#pragma unroll
            for (int j = 0; j < 8; ++j) bf[j] = Bs[kk][tx * 8 + j];
#pragma unroll
            for (int i = 0; i < 8; ++i)
#pragma unroll
                for (int j = 0; j < 8; ++j)
                    acc[i][j] = fmaf(a[i], bf[j], acc[i][j]);
        }
        __syncthreads();
    }

#pragma unroll
    for (int i = 0; i < 8; ++i) {
        float* cp = C + (size_t)(bm + ty * 8 + i) * N + bn + tx * 8;
        *(float4*)(cp + 0) = make_float4(acc[i][0], acc[i][1], acc[i][2], acc[i][3]);
        *(float4*)(cp + 4) = make_float4(acc[i][4], acc[i][5], acc[i][6], acc[i][7]);
    }
}

// ---------------------------------------------------------------------------
// conv + silu (+ l2norm), 3-in-1 and single variants.
// ---------------------------------------------------------------------------
struct ConvArgs {
    const float* pre[3]; const float* w[3]; float* out[3];
    float scale[3]; int do_norm[3];
};
__global__ void conv_silu_norm3(ConvArgs p) {
    const int z = blockIdx.y;
    const float* __restrict__ pre = p.pre[z];
    const float* __restrict__ wv = p.w[z];
    float* __restrict__ out = p.out[z];
    const float scale = p.scale[z];
    const int do_norm = p.do_norm[z];

    const int blk = blockIdx.x;
    const int h = blk & 15;
    const int bt = blk >> 4;
    const int t = bt & (TT - 1);
    const int b = bt >> 10;
    const int dk = threadIdx.x;
    const int c = h * 128 + dk;

    const size_t off = ((size_t)(b * TT + t)) * DD + c;
    float acc = 0.f;
#pragma unroll
    for (int j = 0; j < 4; ++j) {
        const int tt = t - 3 + j;
        const float x = (tt >= 0) ? pre[off + (size_t)(j - 3) * DD] : 0.f;
        acc = fmaf(x, wv[c * 4 + j], acc);
    }
    float x = acc / (1.f + expf(-acc));

    if (do_norm) {
        float ss = x * x;
#pragma unroll
        for (int s = 1; s < 64; s <<= 1) ss += __shfl_xor(ss, s, 64);
        __shared__ float red[2];
        if ((threadIdx.x & 63) == 0) red[threadIdx.x >> 6] = ss;
        __syncthreads();
        const float tot = red[0] + red[1];
        x = x * rsqrtf(tot + 1e-6f) * scale;
    }
    out[off] = x;
}

__global__ void conv_silu_norm(const float* __restrict__ pre, const float* __restrict__ w,
                               float* __restrict__ out, float scale, int do_norm) {
    const int blk = blockIdx.x;
    const int h = blk & 15;
    const int bt = blk >> 4;
    const int t = bt & (TT - 1);
    const int b = bt >> 10;
    const int dk = threadIdx.x;
    const int c = h * 128 + dk;

    const size_t off = ((size_t)(b * TT + t)) * DD + c;
    float acc = 0.f;
#pragma unroll
    for (int j = 0; j < 4; ++j) {
        const int tt = t - 3 + j;
        const float x = (tt >= 0) ? pre[off + (size_t)(j - 3) * DD] : 0.f;
        acc = fmaf(x, w[c * 4 + j], acc);
    }
    float x = acc / (1.f + expf(-acc));

    if (do_norm) {
        float ss = x * x;
#pragma unroll
        for (int s = 1; s < 64; s <<= 1) ss += __shfl_xor(ss, s, 64);
        __shared__ float red[2];
        if ((threadIdx.x & 63) == 0) red[threadIdx.x >> 6] = ss;
        __syncthreads();
        const float tot = red[0] + red[1];
        x = x * rsqrtf(tot + 1e-6f) * scale;
    }
    out[off] = x;
}

// ---------------------------------------------------------------------------
__global__ void beta_kernel(const float* __restrict__ hid, const float* __restrict__ Wb,
                            float* __restrict__ beta) {
    const int m = blockIdx.x;
    const int t = threadIdx.x;
    const int h = t & 15;
    const int sl = t >> 4;

    const float* hp = hid + (size_t)m * DD + sl * 128;
    const float* wp = Wb + (size_t)sl * 128 * HH + h;
    float p = 0.f;
#pragma unroll 8
    for (int i = 0; i < 128; ++i) p = fmaf(hp[i], wp[i * HH], p);

    __shared__ float red[256];
    red[t] = p;
    __syncthreads();
    if (t < HH) {
        float s = 0.f;
#pragma unroll
        for (int i = 0; i < 16; ++i) s += red[i * 16 + t];
        beta[(size_t)m * HH + t] = 1.f / (1.f + expf(-s));
    }
}

// ---------------------------------------------------------------------------
// decay (fallback layout [b,t,h,g]): d values
// ---------------------------------------------------------------------------
__global__ void decay_kernel(const float* __restrict__ g2, const float* __restrict__ A_log,
                             const float* __restrict__ dt_bias, float* __restrict__ decay) {
    const int idx = blockIdx.x * 256 + threadIdx.x;
    const int g = idx & (NG - 1);
    const int h = (idx >> 3) & (HH - 1);
    const float x = g2[idx] + dt_bias[h * NG + g];
    const float sp = (x > 20.f) ? x : log1pf(expf(x));
    decay[idx] = expf(-expf(A_log[h]) * sp);
}

// ---------------------------------------------------------------------------
// LOG-decay, t-tiled [bh][tblk][g][8]
// ---------------------------------------------------------------------------
__global__ void ldecay_kernel_t(const float* __restrict__ g2, const float* __restrict__ A_log,
                                const float* __restrict__ dt_bias, float* __restrict__ ldtr) {
    const int idx = blockIdx.x * 256 + threadIdx.x;   // (b,t,h,g)
    const int g = idx & 7, h = (idx >> 3) & 15;
    const int t = (idx >> 7) & 1023, b = idx >> 17;
    const float x = g2[idx] + dt_bias[h * NG + g];
    const float sp = (x > 20.f) ? x : log1pf(expf(x));
    const float ld = -expf(A_log[h]) * sp;
    const int bh = b * 16 + h, tblk = t >> 3, tj = t & 7;
    ldtr[((size_t)(bh * 128 + tblk)) * 64 + g * 8 + tj] = ld;
}

// ---------------------------------------------------------------------------
// prep_kernel: per (bh, chunk) tile, fully parallel (2048 blocks).
// Outputs pre-split bf16 N, Aq, Kdec and wexpg LUT (verified round 15).
// ---------------------------------------------------------------------------
__launch_bounds__(256)
__global__ void prep_kernel(const float* __restrict__ kt_g, const float* __restrict__ qt_g,
                            const float* __restrict__ ldec, const float* __restrict__ beta,
                            unsigned short* __restrict__ Nh, unsigned short* __restrict__ Nl,
                            unsigned short* __restrict__ Aqh, unsigned short* __restrict__ Aql,
                            unsigned short* __restrict__ Kdh, unsigned short* __restrict__ Kdl,
                            float* __restrict__ wexpg) {
    __shared__ float kt2[128][17];
    __shared__ float qt2[128][17];
    __shared__ float scr0[4][16][17];
    __shared__ float scr1[4][16][17];
    __shared__ float Am[16][21];
    __shared__ float Nm[16][21];
    __shared__ float ld16[16][8];
    __shared__ float Lc[17][8];
    __shared__ float fctl[16][9];
    __shared__ float betas[16];

    const int bid = blockIdx.x;          // bh*64 + ch
    const int bh = bid >> 6, ch = bid & 63;
    const int b = bh >> 4, h = bh & 15;
    const int tid = threadIdx.x;
    const int w = tid >> 6, lane = tid & 63, l15 = lane & 15, lk = lane >> 4;
    const int tb0 = ch * 2, t0 = ch * 16;
    const size_t kbase = (size_t)bh * 131072;
    const size_t tile = (size_t)bid;

    {
        const int c = tid & 127, half = tid >> 7;
        const float* srk = kt_g + kbase + (size_t)(tb0 + half) * 1024 + c * 8;
        float4 a0 = *(const float4*)(srk);
        float4 a1 = *(const float4*)(srk + 4);
        kt2[c][half * 8 + 0] = a0.x; kt2[c][half * 8 + 1] = a0.y;
        kt2[c][half * 8 + 2] = a0.z; kt2[c][half * 8 + 3] = a0.w;
        kt2[c][half * 8 + 4] = a1.x; kt2[c][half * 8 + 5] = a1.y;
        kt2[c][half * 8 + 6] = a1.z; kt2[c][half * 8 + 7] = a1.w;
        const float* srq = qt_g + kbase + (size_t)(tb0 + half) * 1024 + c * 8;
        a0 = *(const float4*)(srq);
        a1 = *(const float4*)(srq + 4);
        qt2[c][half * 8 + 0] = a0.x; qt2[c][half * 8 + 1] = a0.y;
        qt2[c][half * 8 + 2] = a0.z; qt2[c][half * 8 + 3] = a0.w;
        qt2[c][half * 8 + 4] = a1.x; qt2[c][half * 8 + 5] = a1.y;
        qt2[c][half * 8 + 6] = a1.z; qt2[c][half * 8 + 7] = a1.w;
        if (tid < 128) {
            const int t = tid >> 3, g = tid & 7;
            ld16[t][g] = ldec[(size_t)bh * 8192 + (size_t)(tb0 + (t >> 3)) * 64 + g * 8 + (t & 7)];
        }
        if (tid < 16) betas[tid] = beta[((size_t)b * 1024 + t0 + tid) * 16 + h];
    }
    __syncthreads();
    if (tid < 8) {
        float run = 0.f;
        Lc[0][tid] = 0.f;
#pragma unroll
        for (int j = 0; j < 16; ++j) { run += ld16[j][tid]; Lc[j + 1][tid] = run; }
    }
    __syncthreads();

    float apart[4] = {0.f, 0.f, 0.f, 0.f};
    float aqpart[4] = {0.f, 0.f, 0.f, 0.f};
#pragma unroll
    for (int gi = 0; gi < 2; ++gi) {
        const int g = 2 * w + gi;
        float kv[8], qv[8];
        if (lk < 2) {
#pragma unroll
            for (int j = 0; j < 8; ++j) {
                kv[j] = kt2[g * 16 + lk * 8 + j][l15];
                qv[j] = qt2[g * 16 + lk * 8 + j][l15];
            }
        } else {
#pragma unroll
            for (int j = 0; j < 8; ++j) { kv[j] = 0.f; qv[j] = 0.f; }
        }
        bf16x8 kh, kl2, qh2, ql2;
        split8arr(kv, kh, kl2);
        split8arr(qv, qh2, ql2);
        f32x4 gk = (f32x4){0.f, 0.f, 0.f, 0.f};
        f32x4 gq = (f32x4){0.f, 0.f, 0.f, 0.f};
        gk = MFMA16(kh, kh, gk); gk = MFMA16(kh, kl2, gk); gk = MFMA16(kl2, kh, gk);
        gq = MFMA16(qh2, kh, gq); gq = MFMA16(qh2, kl2, gq); gq = MFMA16(ql2, kh, gq);
#pragma unroll
        for (int j = 0; j < 4; ++j) {
            const int t = lk * 4 + j, r = l15;
            const float f = expf(Lc[t + 1][g] - Lc[r + 1][g]);
            apart[j] = fmaf(f, gk[j], apart[j]);
            aqpart[j] = fmaf(f, gq[j], aqpart[j]);
        }
    }
#pragma unroll
    for (int j = 0; j < 4; ++j) {
        scr0[w][lk * 4 + j][l15] = apart[j];
        scr1[w][lk * 4 + j][l15] = aqpart[j];
    }
    __syncthreads();

    {
        const int t = tid >> 4, r = tid & 15;
        const float sa = scr0[0][t][r] + scr0[1][t][r] + scr0[2][t][r] + scr0[3][t][r];
        const float sq = scr1[0][t][r] + scr1[1][t][r] + scr1[2][t][r] + scr1[3][t][r];
        Am[t][r] = (r < t) ? sa : 0.f;
        const float aqm = (r <= t) ? sq : 0.f;
        unsigned short hh, ll;
        bsplit(aqm, hh, ll);
        Aqh[tile * 256 + t * 16 + r] = hh;
        Aql[tile * 256 + t * 16 + r] = ll;
    }
    __syncthreads();

    if (tid < 16) {
        const int col = tid;
        float x[16];
#pragma unroll
        for (int t = 0; t < 16; ++t) {
            float acc = (t == col) ? betas[col] : 0.f;
#pragma unroll
            for (int r = 0; r < 16; ++r)
                if (r < t) acc = fmaf(-betas[t] * Am[t][r], x[r], acc);
            x[t] = acc;
        }
#pragma unroll
        for (int t = 0; t < 16; ++t) Nm[t][col] = x[t];
    } else if (tid >= 128) {
        const int u = tid - 128;
        const int t = u >> 3, g = u & 7;
        wexpg[tile * 128 + u] = expf(Lc[t + 1][g]);
        fctl[t][g] = expf(Lc[16][g] - Lc[t + 1][g]);
    }
    __syncthreads();

    {
        const int t = tid >> 4, r = tid & 15;
        unsigned short hh, ll;
        bsplit(Nm[t][r], hh, ll);
        Nh[tile * 256 + t * 16 + r] = hh;
        Nl[tile * 256 + t * 16 + r] = ll;
    }
    {
        const int c = tid >> 1, t0e = (tid & 1) * 8;
        const int g = c >> 4;
        float vals[8];
#pragma unroll
        for (int j = 0; j < 8; ++j) vals[j] = kt2[c][t0e + j] * fctl[t0e + j][g];
        bf16x8 hi, lo;
        split8arr(vals, hi, lo);
        *(bf16x8*)(Kdh + tile * 2048 + c * 16 + t0e) = hi;
        *(bf16x8*)(Kdl + tile * 2048 + c * 16 + t0e) = lo;
    }
}

// ---------------------------------------------------------------------------
// Serial chunked recurrence, v4: 512 blocks (32 bh x 16 slices of 8 DV cols)
// = 2 blocks/CU for latency hiding. Columns 8..15 of all per-block state are
// identically zero (column dim is preserved through every MFMA), so per-col
// math is bit-identical to v3. Single barrier/chunk, full register prefetch.
// ---------------------------------------------------------------------------
__launch_bounds__(256)
__global__ void chunk_recur(const float* __restrict__ qt_g, const float* __restrict__ kt_g,
                            const float* __restrict__ vt_g,
                            const unsigned short* __restrict__ Nh, const unsigned short* __restrict__ Nl,
                            const unsigned short* __restrict__ Aqh, const unsigned short* __restrict__ Aql,
                            const unsigned short* __restrict__ Kdh, const unsigned short* __restrict__ Kdl,
                            const float* __restrict__ wexpg, float* __restrict__ o) {
    __shared__ float Sl[128][17];
    __shared__ float scr0[2][4][16][17];
    __shared__ float scr1[2][4][16][17];
    __shared__ float vb[2][16][17];
    __shared__ float xb4[4][16][17];
    __shared__ float dl4[4][16][17];

    const int bid = blockIdx.x;
    const int xcd = bid & 7, rr = bid >> 3;        // rr 0..63
    const int bh = xcd * 4 + (rr >> 4);            // 0..31
    const int slice = rr & 15;                     // 0..15 (8 cols each)
    const int b = bh >> 4, h = bh & 15;
    const int tid = threadIdx.x;
    const int w = tid >> 6, lane = tid & 63, l15 = lane & 15, lk = lane >> 4;
    const size_t kbase = (size_t)bh * 131072;
    const size_t obase = ((size_t)b * 1024 * 16 + h) * 128;
    const int cq = w * 32 + lk * 8;
    const int gq2 = cq >> 4;
    const int tv = tid >> 4, u = tid & 15;

    for (int i = tid; i < 128 * 17; i += 256) ((float*)Sl)[i] = 0.f;
    __syncthreads();

    // prefetch ALL operands for chunk 0
    float kr[8], qr[8], vr, ex;
    bf16x8 nhR = zero8(), nlR = zero8(), ahR = zero8(), alR = zero8();
    bf16x8 kdh0 = zero8(), kdl0 = zero8(), kdh1 = zero8(), kdl1 = zero8();
    float w16R0, w16R1;
    {
        const size_t tile0 = (size_t)(bh * 64);
        const size_t rb = kbase + (size_t)(l15 >> 3) * 1024 + (size_t)(l15 & 7);
#pragma unroll
        for (int j = 0; j < 8; ++j) {
            kr[j] = kt_g[rb + (size_t)(cq + j) * 8];
            qr[j] = qt_g[rb + (size_t)(cq + j) * 8];
        }
        vr = (u < 8) ? vt_g[kbase + (size_t)(tv >> 3) * 1024 + (size_t)(slice * 8 + u) * 8 + (tv & 7)] : 0.f;
        ex = wexpg[tile0 * 128 + l15 * 8 + gq2];
        if (lk < 2) {
            nhR = *(const bf16x8*)(Nh + tile0 * 256 + l15 * 16 + lk * 8);
            nlR = *(const bf16x8*)(Nl + tile0 * 256 + l15 * 16 + lk * 8);
            ahR = *(const bf16x8*)(Aqh + tile0 * 256 + l15 * 16 + lk * 8);
            alR = *(const bf16x8*)(Aql + tile0 * 256 + l15 * 16 + lk * 8);
            kdh0 = *(const bf16x8*)(Kdh + tile0 * 2048 + (size_t)((w * 2 + 0) * 16 + l15) * 16 + lk * 8);
            kdl0 = *(const bf16x8*)(Kdl + tile0 * 2048 + (size_t)((w * 2 + 0) * 16 + l15) * 16 + lk * 8);
            kdh1 = *(const bf16x8*)(Kdh + tile0 * 2048 + (size_t)((w * 2 + 1) * 16 + l15) * 16 + lk * 8);
            kdl1 = *(const bf16x8*)(Kdl + tile0 * 2048 + (size_t)((w * 2 + 1) * 16 + l15) * 16 + lk * 8);
        }
        w16R0 = wexpg[tile0 * 128 + 120 + w * 2 + 0];
        w16R1 = wexpg[tile0 * 128 + 120 + w * 2 + 1];
    }

    for (int ch = 0; ch < 64; ++ch) {
        const int cur = ch & 1;
        const int cn = (ch + 1 < 64) ? (ch + 1) : ch;
        const size_t tilen = (size_t)(bh * 64 + cn);

        // stage v for current chunk (double-buffered; cols >=8 are zero)
        vb[cur][tv][u] = vr;

        // ---- phase A: E0/Oq partials from registers ----
        {
            float kv[8], qv[8], sv[8];
#pragma unroll
            for (int j = 0; j < 8; ++j) {
                kv[j] = kr[j] * ex;
                qv[j] = qr[j] * ex;
                sv[j] = (l15 < 8) ? Sl[cq + j][l15] : 0.f;
            }
            bf16x8 wh, wl, qh, ql, sh, sl2;
            split8arr(kv, wh, wl);
            split8arr(qv, qh, ql);
            split8arr(sv, sh, sl2);
            f32x4 e0 = (f32x4){0.f, 0.f, 0.f, 0.f};
            f32x4 oq = (f32x4){0.f, 0.f, 0.f, 0.f};
            e0 = MFMA16(wh, sh, e0); e0 = MFMA16(wh, sl2, e0); e0 = MFMA16(wl, sh, e0);
            oq = MFMA16(qh, sh, oq); oq = MFMA16(qh, sl2, oq); oq = MFMA16(ql, sh, oq);
#pragma unroll
            for (int j = 0; j < 4; ++j) {
                scr0[cur][w][lk * 4 + j][l15] = e0[j];
                scr1[cur][w][lk * 4 + j][l15] = oq[j];
            }
        }

        // ---- prefetch next chunk k/q/v/ex (clamped) ----
        {
            const size_t gb2 = kbase + (size_t)(cn * 2) * 1024;
            const size_t rb2 = gb2 + (size_t)(l15 >> 3) * 1024 + (size_t)(l15 & 7);
#pragma unroll
            for (int j = 0; j < 8; ++j) {
                kr[j] = kt_g[rb2 + (size_t)(cq + j) * 8];
                qr[j] = qt_g[rb2 + (size_t)(cq + j) * 8];
            }
            vr = (u < 8) ? vt_g[gb2 + (size_t)(tv >> 3) * 1024 + (size_t)(slice * 8 + u) * 8 + (tv & 7)] : 0.f;
            ex = wexpg[tilen * 128 + l15 * 8 + gq2];
        }

        __syncthreads();   // the ONLY barrier per chunk

        // ---- phase B (all waves redundant): x = v - sum(E0); d = N@x ----
        bf16x8 dh2, dl2;
        {
            const int tt = lane >> 2, v0 = (lane & 3) * 4;
#pragma unroll
            for (int uu = 0; uu < 4; ++uu) {
                const int v = v0 + uu;
                xb4[w][tt][v] = vb[cur][tt][v] -
                    (scr0[cur][0][tt][v] + scr0[cur][1][tt][v] +
                     scr0[cur][2][tt][v] + scr0[cur][3][tt][v]);
            }
            float xv[8];
            if (lk < 2) {
#pragma unroll
                for (int j = 0; j < 8; ++j) xv[j] = xb4[w][lk * 8 + j][l15];
            } else {
#pragma unroll
                for (int j = 0; j < 8; ++j) xv[j] = 0.f;
            }
            bf16x8 xh, xl;
            split8arr(xv, xh, xl);
            f32x4 d = (f32x4){0.f, 0.f, 0.f, 0.f};
            d = MFMA16(nhR, xh, d); d = MFMA16(nhR, xl, d); d = MFMA16(nlR, xh, d);
#pragma unroll
            for (int j = 0; j < 4; ++j) dl4[w][lk * 4 + j][l15] = d[j];

            float dv[8];
            if (lk < 2) {
#pragma unroll
                for (int j = 0; j < 8; ++j) dv[j] = dl4[w][lk * 8 + j][l15];
            } else {
#pragma unroll
                for (int j = 0; j < 8; ++j) dv[j] = 0.f;
            }
            split8arr(dv, dh2, dl2);

            // o output (wave 0 only; cols < 8 of this slice)
            if (w == 0) {
                f32x4 oc;
#pragma unroll
                for (int j = 0; j < 4; ++j) {
                    const int t = lk * 4 + j;
                    oc[j] = scr1[cur][0][t][l15] + scr1[cur][1][t][l15] +
                            scr1[cur][2][t][l15] + scr1[cur][3][t][l15];
                }
                oc = MFMA16(ahR, dh2, oc); oc = MFMA16(ahR, dl2, oc); oc = MFMA16(alR, dh2, oc);
                if (l15 < 8) {
#pragma unroll
                    for (int j = 0; j < 4; ++j)
                        o[obase + (size_t)(ch * 16 + lk * 4 + j) * 2048 + slice * 8 + l15] = oc[j];
                }
            }
        }

        // ---- prefetch next N/Aq (consumed; safe to overwrite) ----
        if (lk < 2) {
            nhR = *(const bf16x8*)(Nh + tilen * 256 + l15 * 16 + lk * 8);
            nlR = *(const bf16x8*)(Nl + tilen * 256 + l15 * 16 + lk * 8);
            ahR = *(const bf16x8*)(Aqh + tilen * 256 + l15 * 16 + lk * 8);
            alR = *(const bf16x8*)(Aql + tilen * 256 + l15 * 16 + lk * 8);
        }

        // ---- phase C: S update (own rows; operands in registers) ----
        {
            f32x4 sc;
#pragma unroll
            for (int j = 0; j < 4; ++j) sc[j] = Sl[(w * 2 + 0) * 16 + lk * 4 + j][l15] * w16R0;
            sc = MFMA16(kdh0, dh2, sc); sc = MFMA16(kdh0, dl2, sc); sc = MFMA16(kdl0, dh2, sc);
#pragma unroll
            for (int j = 0; j < 4; ++j) Sl[(w * 2 + 0) * 16 + lk * 4 + j][l15] = sc[j];

            f32x4 sc1;
#pragma unroll
            for (int j = 0; j < 4; ++j) sc1[j] = Sl[(w * 2 + 1) * 16 + lk * 4 + j][l15] * w16R1;
            sc1 = MFMA16(kdh1, dh2, sc1); sc1 = MFMA16(kdh1, dl2, sc1); sc1 = MFMA16(kdl1, dh2, sc1);
#pragma unroll
            for (int j = 0; j < 4; ++j) Sl[(w * 2 + 1) * 16 + lk * 4 + j][l15] = sc1[j];
        }

        // ---- prefetch next Kd/w16 (consumed; safe to overwrite) ----
        if (lk < 2) {
            kdh0 = *(const bf16x8*)(Kdh + tilen * 2048 + (size_t)((w * 2 + 0) * 16 + l15) * 16 + lk * 8);
            kdl0 = *(const bf16x8*)(Kdl + tilen * 2048 + (size_t)((w * 2 + 0) * 16 + l15) * 16 + lk * 8);
            kdh1 = *(const bf16x8*)(Kdh + tilen * 2048 + (size_t)((w * 2 + 1) * 16 + l15) * 16 + lk * 8);
            kdl1 = *(const bf16x8*)(Kdl + tilen * 2048 + (size_t)((w * 2 + 1) * 16 + l15) * 16 + lk * 8);
        }
        w16R0 = wexpg[tilen * 128 + 120 + w * 2 + 0];
        w16R1 = wexpg[tilen * 128 + 120 + w * 2 + 1];
    }
}

// ---------------------------------------------------------------------------
// Old-layout recurrence (fallback path only).
// ---------------------------------------------------------------------------
__launch_bounds__(256, 4)
__global__ void recur_kernel(const float* __restrict__ q, const float* __restrict__ k,
                             const float* __restrict__ vv, const float* __restrict__ decay,
                             const float* __restrict__ beta, float* __restrict__ o) {
    const int blk = blockIdx.x;
    const int vblk = blk & 31;
    const int bh = blk >> 5;
    const int b = bh >> 4, h = bh & 15;
    const int w = threadIdx.x >> 6;
    const int lane = threadIdx.x & 63;
    const int vi = vblk * 4 + w;

    float S0 = 0.f, S1 = 0.f;
    const size_t strideT = (size_t)HH * DV;
    const size_t strideT2 = strideT >> 1;
    const size_t base = ((size_t)b * TT * HH + h) * DV;

    const float2* kp = (const float2*)(k + base) + lane;
    const float2* qp = (const float2*)(q + base) + lane;
    const float* vp = vv + base + vi;
    const float* bp = beta + (size_t)b * TT * HH + h;
    const float* dp = decay + ((size_t)b * TT * HH + h) * NG + (lane >> 3);

    float2 kv = kp[0], qv = qp[0];
    float vtv = vp[0], bt = bp[0], dt = dp[0];

    for (int t = 0; t < TT; ++t) {
        const float2 kc = kv, qc = qv;
        const float vc = vtv, bc = bt, dc = dt;

        const int tn = (t + 1 < TT) ? (t + 1) : t;
        kv = kp[(size_t)tn * strideT2];
        qv = qp[(size_t)tn * strideT2];
        vtv = vp[(size_t)tn * strideT];
        bt = bp[(size_t)tn * HH];
        dt = dp[(size_t)tn * HH * NG];

        S0 *= dc;
        S1 *= dc;
        float e = fmaf(kc.x, S0, kc.y * S1);
        e = dpp_sum64(e);
        const float err = readlanef(e, 63);
        const float delta = bc * (vc - err);
        S0 = fmaf(kc.x, delta, S0);
        S1 = fmaf(kc.y, delta, S1);
        float oo = fmaf(qc.x, S0, qc.y * S1);
        oo = dpp_sum64(oo);
        if (lane == 63) o[base + (size_t)t * strideT + vi] = oo;
    }
}

// ---------------------------------------------------------------------------
// Gated RMSNorm -> fp32 y (fallback)
// ---------------------------------------------------------------------------
__global__ void gated_rmsnorm(const float* __restrict__ o,
                              const float* __restrict__ gpre, const float* __restrict__ bg,
                              const float* __restrict__ norm_w, float* __restrict__ y) {
    const int blk = blockIdx.x;
    const int h = blk & 15;
    const int dv = threadIdx.x;
    const size_t off = (size_t)blk * DV + dv;

    const float ov = o[off];
    const float g = gpre[off] + bg[h * 128 + dv];
    const float yv = ov * (g / (1.f + expf(-g)));

    float ss = yv * yv;
#pragma unroll
    for (int s = 1; s < 64; s <<= 1) ss += __shfl_xor(ss, s, 64);
    __shared__ float red[2];
    if ((threadIdx.x & 63) == 0) red[threadIdx.x >> 6] = ss;
    __syncthreads();
    const float mean = (red[0] + red[1]) * (1.f / 128.f);
    y[off] = yv * rsqrtf(mean + 1e-5f) * norm_w[dv];
}

// ---------------------------------------------------------------------------
// Gated RMSNorm -> bf16 hi/lo split y
// ---------------------------------------------------------------------------
__global__ void gated_rmsnorm_split(const float* __restrict__ o,
                                    const float* __restrict__ gpre, const float* __restrict__ bg,
                                    const float* __restrict__ norm_w,
                                    unsigned short* __restrict__ yh,
                                    unsigned short* __restrict__ yl) {
    const int blk = blockIdx.x;
    const int h = blk & 15;
    const int dv = threadIdx.x;
    const size_t off = (size_t)blk * DV + dv;

    const float ov = o[off];
    const float g = gpre[off] + bg[h * 128 + dv];
    const float yv = ov * (g / (1.f + expf(-g)));

    float ss = yv * yv;
#pragma unroll
    for (int s = 1; s < 64; s <<= 1) ss += __shfl_xor(ss, s, 64);
    __shared__ float red[2];
    if ((threadIdx.x & 63) == 0) red[threadIdx.x >> 6] = ss;
    __syncthreads();
    const float mean = (red[0] + red[1]) * (1.f / 128.f);
    const float y = yv * rsqrtf(mean + 1e-5f) * norm_w[dv];
    unsigned short hh, ll;
    bsplit(y, hh, ll);
    yh[off] = hh;
    yl[off] = ll;
}

// ---------------------------------------------------------------------------
extern "C" void kernel_launch(void* const* d_in, const int* in_sizes, int n_in,
                              void* d_out, int out_size, void* d_ws, size_t ws_size,
                              hipStream_t stream) {
    const float* hid    = (const float*)d_in[0];
    const float* Wq     = (const float*)d_in[1];
    const float* Wk     = (const float*)d_in[2];
    const float* Wv     = (const float*)d_in[3];
    const float* conv_q = (const float*)d_in[4];
    const float* conv_k = (const float*)d_in[5];
    const float* conv_v = (const float*)d_in[6];
    const float* Wf1    = (const float*)d_in[7];
    const float* Wf2    = (const float*)d_in[8];
    const float* Wb     = (const float*)d_in[9];
    const float* A_log  = (const float*)d_in[10];
    const float* dt_bias= (const float*)d_in[11];
    const float* Wg     = (const float*)d_in[12];
    const float* bg     = (const float*)d_in[13];
    const float* norm_w = (const float*)d_in[14];
    const float* Wo     = (const float*)d_in[15];
    float* out = (float*)d_out;

    const size_t N1  = (size_t)2048 * 2048;
    const size_t N1B = N1 * 4;
    const int M = BB * TT;

    const size_t NEED_NEW = 9 * N1B + 4390912;

    if (ws_size >= NEED_NEW) {
        // ---------------- MFMA split-precision path ----------------
        char* W = (char*)d_ws;
        unsigned short* hidh = (unsigned short*)W;
        unsigned short* hidl = hidh + N1;
        float* o = (float*)W;
        char* RB = W + N1B;
        unsigned short* Wqth = (unsigned short*)RB;
        unsigned short* Wqtl = Wqth + N1;
        unsigned short* Wkth = Wqtl + N1;
        unsigned short* Wktl = Wkth + N1;
        unsigned short* Wvth = Wktl + N1;
        unsigned short* Wvtl = Wvth + N1;
        unsigned short* Wgth = Wvtl + N1;
        unsigned short* Wgtl = Wgth + N1;
        float* qn = (float*)RB;
        float* kn = qn + N1;
        float* vn = kn + N1;
        unsigned short* Nh  = (unsigned short*)qn;
        unsigned short* Nl  = Nh + 524288;
        unsigned short* Aqh = Nl + 524288;
        unsigned short* Aql = Aqh + 524288;
        float* wexpg = (float*)(Aql + 524288);
        unsigned short* Kdh = (unsigned short*)kn;
        unsigned short* Kdl = Kdh + 4194304;
        char* RC = W + 5 * N1B;
        float* qpre = (float*)RC;
        float* kpre = qpre + N1;
        float* vpre = kpre + N1;
        float* gpre = vpre + N1;
        float* qn_t = qpre;
        float* kn_t = kpre;
        float* vn_t = vpre;
        unsigned short* Woth = (unsigned short*)RC;
        unsigned short* Wotl = Woth + N1;
        unsigned short* yh = (unsigned short*)(RC + N1B);
        unsigned short* yl = yh + N1;
        char* RD = W + 9 * N1B;
        float* g1b   = (float*)RD;
        float* g2b   = g1b + 262144;
        float* betab = g2b + 262144;
        float* ldecb = betab + 32768;
        unsigned short* wf1th = (unsigned short*)(ldecb + 262144);
        unsigned short* wf1tl = wf1th + 262144;

        // 1. splits / transposes
        split_mat<<<1024, 256, 0, stream>>>(hid, hidh, hidl);
        TS4 ts;
        ts.in[0] = Wq; ts.oh[0] = Wqth; ts.ol[0] = Wqtl;
        ts.in[1] = Wk; ts.oh[1] = Wkth; ts.ol[1] = Wktl;
        ts.in[2] = Wv; ts.oh[2] = Wvth; ts.ol[2] = Wvtl;
        ts.in[3] = Wg; ts.oh[3] = Wgth; ts.ol[3] = Wgtl;
        transpose_split4<<<dim3(32, 32, 4), 256, 0, stream>>>(ts);
        transpose_split<<<dim3(2, 32), 256, 0, stream>>>(Wf1, wf1th, wf1tl, 128, 2048);

        // 2. input projections: q/k/v/g PURE BF16 (NM=1, mode 1, grid 64x16),
        //    Wf1 split-3 (NM=3, mode 2, grid 1x16).
        GemmArgs fa;
        fa.Ah = hidh; fa.Al = hidl;
        fa.Bh[0] = Wqth; fa.Bl[0] = Wqtl; fa.C[0] = qpre;
        fa.Bh[1] = Wkth; fa.Bl[1] = Wktl; fa.C[1] = kpre;
        fa.Bh[2] = Wvth; fa.Bl[2] = Wvtl; fa.C[2] = vpre;
        fa.Bh[3] = Wgth; fa.Bl[3] = Wgtl; fa.C[3] = gpre;
        fa.Bh[4] = wf1th; fa.Bl[4] = wf1tl; fa.C[4] = g1b;
        gemm_split<1><<<dim3(64, 16), 256, 0, stream>>>(fa, 1);
        gemm_split<3><<<dim3(1, 16), 256, 0, stream>>>(fa, 2);

        // 3. beta, g2, log-decay (t-tiled)
        beta_kernel<<<M, 256, 0, stream>>>(hid, Wb, betab);
        sgemm128<<<dim3(1, 16), 256, 0, stream>>>(g1b, Wf2, g2b, M, 128, 128);
        ldecay_kernel_t<<<(M * HH * NG) / 256, 256, 0, stream>>>(g2b, A_log, dt_bias, ldecb);

        // 4. conv + silu (+ l2norm)
        ConvArgs ca;
        ca.pre[0] = qpre; ca.w[0] = conv_q; ca.out[0] = qn; ca.scale[0] = SCALE_Q; ca.do_norm[0] = 1;
        ca.pre[1] = kpre; ca.w[1] = conv_k; ca.out[1] = kn; ca.scale[1] = 1.f;     ca.do_norm[1] = 1;
        ca.pre[2] = vpre; ca.w[2] = conv_v; ca.out[2] = vn; ca.scale[2] = 1.f;     ca.do_norm[2] = 0;
        conv_silu_norm3<<<dim3(M * HH, 3), 128, 0, stream>>>(ca);

        // 5. t-tile transpose
        T3 tt;
        tt.in[0] = qn; tt.out[0] = qn_t;
        tt.in[1] = kn; tt.out[1] = kn_t;
        tt.in[2] = vn; tt.out[2] = vn_t;
        transpose_tile3<<<dim3(4096, 3), 256, 0, stream>>>(tt);

        // 6. prep (parallel) + serial chunked recurrence (512 blocks, 2/CU)
        prep_kernel<<<2048, 256, 0, stream>>>(kn_t, qn_t, ldecb, betab,
                                              Nh, Nl, Aqh, Aql, Kdh, Kdl, wexpg);
        chunk_recur<<<512, 256, 0, stream>>>(qn_t, kn_t, vn_t,
                                             Nh, Nl, Aqh, Aql, Kdh, Kdl, wexpg, o);

        // 7. transpose Wo (over dead qn_t)
        transpose_split<<<dim3(32, 32), 256, 0, stream>>>(Wo, Woth, Wotl, 2048, 2048);

        // 8. gated rmsnorm -> y split (over dead kn_t)
        gated_rmsnorm_split<<<M * HH, 128, 0, stream>>>(o, gpre, bg, norm_w, yh, yl);

        // 9. output projection (split-2, NM=2, mode 0)
        GemmArgs oa;
        oa.Ah = yh; oa.Al = yl;
        for (int i = 0; i < 5; ++i) { oa.Bh[i] = Woth; oa.Bl[i] = Wotl; oa.C[i] = out; }
        gemm_split<2><<<dim3(16, 16), 256, 0, stream>>>(oa, 0);
    } else {
        // ---------------- fallback: fp32 path ----------------
        float* ws = (float*)d_ws;
        float* qpre = ws + 0 * N1;
        float* kpre = ws + 1 * N1;
        float* vpre = ws + 2 * N1;
        float* gpre = ws + 3 * N1;
        float* qn   = ws + 4 * N1;
        float* kn   = ws + 5 * N1;
        float* vn   = ws + 6 * N1;
        float* g1b  = ws + 7 * N1;
        float* g2b  = g1b + (size_t)BB * TT * DV;
        float* betab= g2b + (size_t)BB * TT * HH * NG;
        float* decayb = betab + (size_t)BB * TT * HH;
        float* o = qpre;
        float* y = vpre;

        sgemm128<<<dim3(16, 16), 256, 0, stream>>>(hid, Wq, qpre, M, 2048, 2048);
        sgemm128<<<dim3(16, 16), 256, 0, stream>>>(hid, Wk, kpre, M, 2048, 2048);
        sgemm128<<<dim3(16, 16), 256, 0, stream>>>(hid, Wv, vpre, M, 2048, 2048);
        sgemm128<<<dim3(16, 16), 256, 0, stream>>>(hid, Wg, gpre, M, 2048, 2048);
        sgemm128<<<dim3(1, 16), 256, 0, stream>>>(hid, Wf1, g1b, M, 128, 2048);
        sgemm128<<<dim3(1, 16), 256, 0, stream>>>(g1b, Wf2, g2b, M, 128, 128);
        beta_kernel<<<M, 256, 0, stream>>>(hid, Wb, betab);

        conv_silu_norm<<<M * HH, 128, 0, stream>>>(qpre, conv_q, qn, SCALE_Q, 1);
        conv_silu_norm<<<M * HH, 128, 0, stream>>>(kpre, conv_k, kn, 1.f, 1);
        conv_silu_norm<<<M * HH, 128, 0, stream>>>(vpre, conv_v, vn, 1.f, 0);

        decay_kernel<<<(M * HH * NG) / 256, 256, 0, stream>>>(g2b, A_log, dt_bias, decayb);

        recur_kernel<<<BB * HH * (DV / 4), 256, 0, stream>>>(qn, kn, vn, decayb, betab, o);

        gated_rmsnorm<<<M * HH, 128, 0, stream>>>(o, gpre, bg, norm_w, y);

        sgemm128<<<dim3(16, 16), 256, 0, stream>>>(y, Wo, out, M, 2048, 2048);
    }
}

// Round 23
// 480.371 us; speedup vs baseline: 1.0849x; 1.0849x over previous
//
#include <hip/hip_runtime.h>
#include <hip/hip_bf16.h>
#include <math.h>

// Problem constants (fixed by setup_inputs)
#define BB 2
#define TT 1024
#define DD 2048
#define HH 16
#define DK 128
#define DV 128
#define NG 8
#define GG 16
#define SCALE_Q 0.08838834764831845f  // 128^-0.5

typedef __attribute__((ext_vector_type(8))) short bf16x8;
typedef __attribute__((ext_vector_type(4))) float f32x4;
typedef __attribute__((ext_vector_type(4))) unsigned int u32x4;

#define MFMA16(a, b, c) __builtin_amdgcn_mfma_f32_16x16x32_bf16((a), (b), (c), 0, 0, 0)

// bf16 split helpers (RNE)
__device__ __forceinline__ unsigned short f2bf(float v) {
    unsigned u = __float_as_uint(v);
    return (unsigned short)((u + 0x7FFFu + ((u >> 16) & 1u)) >> 16);
}
__device__ __forceinline__ float bf2f(unsigned short h) {
    return __uint_as_float(((unsigned)h) << 16);
}
__device__ __forceinline__ void bsplit(float v, unsigned short& h, unsigned short& l) {
    h = f2bf(v);
    l = f2bf(v - bf2f(h));
}
// Fast pairwise split via v_cvt_pk_bf16_f32 (HW RNE, ~24 VALU ops vs ~80).
__device__ __forceinline__ void split8arr(const float* v, bf16x8& hi, bf16x8& lo) {
    union U { u32x4 u; bf16x8 s; } H, L;
#pragma unroll
    for (int p = 0; p < 4; ++p) {
        const float a = v[2 * p], b = v[2 * p + 1];
        unsigned hpk;
        asm("v_cvt_pk_bf16_f32 %0, %1, %2" : "=v"(hpk) : "v"(a), "v"(b));
        const float ra = __uint_as_float(hpk << 16);
        const float rb = __uint_as_float(hpk & 0xFFFF0000u);
        unsigned lpk;
        asm("v_cvt_pk_bf16_f32 %0, %1, %2" : "=v"(lpk) : "v"(a - ra), "v"(b - rb));
        H.u[p] = hpk;
        L.u[p] = lpk;
    }
    hi = H.s;
    lo = L.s;
}
__device__ __forceinline__ bf16x8 zero8() {
    bf16x8 z;
#pragma unroll
    for (int i = 0; i < 8; ++i) z[i] = 0;
    return z;
}

// ---------------------------------------------------------------------------
// DPP wave64 sum (fallback recurrence only).
// ---------------------------------------------------------------------------
__device__ __forceinline__ float dpp_sum64(float x) {
    x += __int_as_float(__builtin_amdgcn_update_dpp(0, __float_as_int(x), 0x111, 0xf, 0xf, true));
    x += __int_as_float(__builtin_amdgcn_update_dpp(0, __float_as_int(x), 0x112, 0xf, 0xf, true));
    x += __int_as_float(__builtin_amdgcn_update_dpp(0, __float_as_int(x), 0x114, 0xf, 0xf, true));
    x += __int_as_float(__builtin_amdgcn_update_dpp(0, __float_as_int(x), 0x118, 0xf, 0xf, true));
    x += __int_as_float(__builtin_amdgcn_update_dpp(0, __float_as_int(x), 0x142, 0xa, 0xf, false));
    x += __int_as_float(__builtin_amdgcn_update_dpp(0, __float_as_int(x), 0x143, 0xc, 0xf, false));
    return x;
}
__device__ __forceinline__ float readlanef(float x, int l) {
    return __int_as_float(__builtin_amdgcn_readlane(__float_as_int(x), l));
}

// ---------------------------------------------------------------------------
// split: fp32 [n] -> bf16 hi/lo
// ---------------------------------------------------------------------------
__global__ void split_mat(const float* __restrict__ in, unsigned short* __restrict__ oh,
                          unsigned short* __restrict__ ol) {
    const int i0 = (blockIdx.x * 256 + threadIdx.x) * 16;
#pragma unroll
    for (int r = 0; r < 4; ++r) {
        const float4 v = *(const float4*)(in + i0 + r * 4);
        unsigned short h0, l0, h1, l1, h2, l2, h3, l3;
        bsplit(v.x, h0, l0); bsplit(v.y, h1, l1);
        bsplit(v.z, h2, l2); bsplit(v.w, h3, l3);
        short4 hh; hh.x = (short)h0; hh.y = (short)h1; hh.z = (short)h2; hh.w = (short)h3;
        short4 ll; ll.x = (short)l0; ll.y = (short)l1; ll.z = (short)l2; ll.w = (short)l3;
        *(short4*)(oh + i0 + r * 4) = hh;
        *(short4*)(ol + i0 + r * 4) = ll;
    }
}

// ---------------------------------------------------------------------------
// transpose + split: in fp32 [Kin][Nin] -> out bf16 hi/lo [Nin][Kin]
// ---------------------------------------------------------------------------
__device__ __forceinline__ void tsplit_body(const float* __restrict__ in,
                                            unsigned short* __restrict__ oh,
                                            unsigned short* __restrict__ ol,
                                            int Nin, int Kin, int bx, int by, int tid) {
    __shared__ float t[64][65];
    const int c4 = (tid & 15) * 4, r0 = tid >> 4;
#pragma unroll
    for (int rep = 0; rep < 4; ++rep) {
        const int r = r0 + rep * 16;
        const float4 v = *(const float4*)(in + (size_t)(by * 64 + r) * Nin + bx * 64 + c4);
        t[r][c4] = v.x; t[r][c4 + 1] = v.y; t[r][c4 + 2] = v.z; t[r][c4 + 3] = v.w;
    }
    __syncthreads();
#pragma unroll
    for (int rep = 0; rep < 4; ++rep) {
        const int n = r0 + rep * 16;
        short4 hh, ll;
        unsigned short h, l;
        bsplit(t[c4 + 0][n], h, l); hh.x = (short)h; ll.x = (short)l;
        bsplit(t[c4 + 1][n], h, l); hh.y = (short)h; ll.y = (short)l;
        bsplit(t[c4 + 2][n], h, l); hh.z = (short)h; ll.z = (short)l;
        bsplit(t[c4 + 3][n], h, l); hh.w = (short)h; ll.w = (short)l;
        const size_t o = (size_t)(bx * 64 + n) * Kin + by * 64 + c4;
        *(short4*)(oh + o) = hh;
        *(short4*)(ol + o) = ll;
    }
}

__global__ void transpose_split(const float* __restrict__ in, unsigned short* __restrict__ oh,
                                unsigned short* __restrict__ ol, int Nin, int Kin) {
    tsplit_body(in, oh, ol, Nin, Kin, blockIdx.x, blockIdx.y, threadIdx.x);
}

struct TS4 { const float* in[4]; unsigned short* oh[4]; unsigned short* ol[4]; };
__global__ void transpose_split4(TS4 p) {
    const int z = blockIdx.z;
    tsplit_body(p.in[z], p.oh[z], p.ol[z], 2048, 2048, blockIdx.x, blockIdx.y, threadIdx.x);
}

// ---------------------------------------------------------------------------
// t-tile transpose x3: in [B][1024][2048] -> out tiled [bh][tblk][cl][8]
// ---------------------------------------------------------------------------
struct T3 { const float* in[3]; float* out[3]; };
__global__ void transpose_tile3(T3 p) {
    __shared__ float tl[8][128];
    const int z = blockIdx.y;
    const float* __restrict__ in = p.in[z];
    float* __restrict__ out = p.out[z];
    const int blk = blockIdx.x;
    const int bh = blk >> 7, tblk = blk & 127;
    const int b = bh >> 4, h = bh & 15;
    const int tid = threadIdx.x;

    const int tt = tid >> 5, c4 = (tid & 31) * 4;
    const float4 v = *(const float4*)(in + ((size_t)(b * 1024 + tblk * 8 + tt)) * 2048 + h * 128 + c4);
    tl[tt][c4] = v.x; tl[tt][c4 + 1] = v.y; tl[tt][c4 + 2] = v.z; tl[tt][c4 + 3] = v.w;
    __syncthreads();

    const int cl = tid >> 1, tj0 = (tid & 1) * 4;
    float4 w4;
    w4.x = tl[tj0 + 0][cl]; w4.y = tl[tj0 + 1][cl];
    w4.z = tl[tj0 + 2][cl]; w4.w = tl[tj0 + 3][cl];
    *(float4*)(out + ((size_t)blk * 128 + cl) * 8 + tj0) = w4;
}

// ---------------------------------------------------------------------------
// Split-precision bf16 MFMA GEMM, XCD-swizzled, NM = MFMA count (COMPILE-TIME):
//   NM=1: pure bf16 (Ah x Bh), stages 2 arrays  -- fused input projections
//   NM=2: split-2 (Ah x (Bh+Bl)), stages 3      -- output projection
//   NM=3: split-3 (hh+hl+lh), stages 4          -- Wf1 (decay-sensitive)
// mode 0: single output sel0, ldc 2048, nloc = bx*128   (out-proj, grid 16x16)
// mode 1: fused q/k/v/g, grid 64x16, sel = bx>>4        (input projections)
// mode 2: Wf1 single, grid 1x16, sel=4, nloc=0, ldc=128
// ---------------------------------------------------------------------------
struct GemmArgs {
    const unsigned short* Ah; const unsigned short* Al;
    const unsigned short* Bh[5]; const unsigned short* Bl[5];
    float* C[5];
};

#define AHI 0
#define ALO 8192
#define BHI 16384
#define BLO 24576

#define GL2LDS(g, s) __builtin_amdgcn_global_load_lds( \
    (const __attribute__((address_space(1))) void*)(g), \
    (__attribute__((address_space(3))) void*)(s), 16, 0, 0)

template <int NM>
__launch_bounds__(256, 3)
__global__ void gemm_split(GemmArgs p, int mode) {
    __shared__ __attribute__((aligned(16))) char lds[32768];
    const int tid = threadIdx.x;

    // XCD-aware bijective swizzle (gridDim.y == 16 for all launches)
    int bx, by;
    {
        const int gw = gridDim.x;
        const int lin = blockIdx.y * gw + blockIdx.x;
        const int per = (gw * 16) >> 3;
        const int swz = (lin & 7) * per + (lin >> 3);
        bx = swz >> 4;
        by = swz & 15;
    }

    int sel, nloc, ldc;
    if (mode == 1)      { sel = bx >> 4; nloc = (bx & 15) * 128; ldc = 2048; }
    else if (mode == 2) { sel = 4;       nloc = 0;               ldc = 128;  }
    else                { sel = 0;       nloc = bx * 128;        ldc = 2048; }

    const unsigned short* Asrc_h = p.Ah + (size_t)(by * 128) * 2048;
    const unsigned short* Asrc_l = p.Al + (size_t)(by * 128) * 2048;
    const unsigned short* Bsrc_h = p.Bh[sel] + (size_t)nloc * 2048;
    const unsigned short* Bsrc_l = p.Bl[sel] + (size_t)nloc * 2048;

    const int r0 = tid >> 2, ps0 = tid & 3;
    const int r1 = (tid + 256) >> 2, ps1 = tid & 3;
    const size_t ga0 = (size_t)r0 * 2048 + (size_t)((ps0 ^ ((r0 >> 1) & 3)) * 8);
    const size_t ga1 = (size_t)r1 * 2048 + (size_t)((ps1 ^ ((r1 >> 1) & 3)) * 8);
    const int lb0 = (tid & 192) * 16;
    const int lb1 = (256 + (tid & 192)) * 16;

    const int lane = tid & 63;
    const int l15 = lane & 15, kgrp = lane >> 4;
    const int w = tid >> 6, wm = w >> 1, wn = w & 1;
    const int swzf = kgrp ^ ((l15 >> 1) & 3);
    const int fro = l15 * 64 + swzf * 16;
    const int aoff = wm * 4096, boff = wn * 4096;

    f32x4 acc[4][4];
#pragma unroll
    for (int i = 0; i < 4; ++i)
#pragma unroll
        for (int j = 0; j < 4; ++j) acc[i][j] = (f32x4){0.f, 0.f, 0.f, 0.f};

    for (int k0 = 0; k0 < 2048; k0 += 32) {
        __syncthreads();
        GL2LDS(Asrc_h + k0 + ga0, lds + AHI + lb0);
        GL2LDS(Asrc_h + k0 + ga1, lds + AHI + lb1);
        if constexpr (NM >= 3) {
            GL2LDS(Asrc_l + k0 + ga0, lds + ALO + lb0);
            GL2LDS(Asrc_l + k0 + ga1, lds + ALO + lb1);
        }
        GL2LDS(Bsrc_h + k0 + ga0, lds + BHI + lb0);
        GL2LDS(Bsrc_h + k0 + ga1, lds + BHI + lb1);
        if constexpr (NM >= 2) {
            GL2LDS(Bsrc_l + k0 + ga0, lds + BLO + lb0);
            GL2LDS(Bsrc_l + k0 + ga1, lds + BLO + lb1);
        }
        __syncthreads();

        bf16x8 ah[4], bh4[4];
#pragma unroll
        for (int f = 0; f < 4; ++f) {
            ah[f]  = *(const bf16x8*)(lds + AHI + aoff + f * 1024 + fro);
            bh4[f] = *(const bf16x8*)(lds + BHI + boff + f * 1024 + fro);
        }
        if constexpr (NM == 1) {
#pragma unroll
            for (int i = 0; i < 4; ++i)
#pragma unroll
                for (int j = 0; j < 4; ++j)
                    acc[i][j] = MFMA16(ah[i], bh4[j], acc[i][j]);
        } else if constexpr (NM == 2) {
            bf16x8 bl4[4];
#pragma unroll
            for (int f = 0; f < 4; ++f)
                bl4[f] = *(const bf16x8*)(lds + BLO + boff + f * 1024 + fro);
#pragma unroll
            for (int i = 0; i < 4; ++i)
#pragma unroll
                for (int j = 0; j < 4; ++j) {
                    acc[i][j] = MFMA16(ah[i], bh4[j], acc[i][j]);
                    acc[i][j] = MFMA16(ah[i], bl4[j], acc[i][j]);
                }
        } else {
            bf16x8 bl4[4], al4[4];
#pragma unroll
            for (int f = 0; f < 4; ++f) {
                bl4[f] = *(const bf16x8*)(lds + BLO + boff + f * 1024 + fro);
                al4[f] = *(const bf16x8*)(lds + ALO + aoff + f * 1024 + fro);
            }
#pragma unroll
            for (int i = 0; i < 4; ++i)
#pragma unroll
                for (int j = 0; j < 4; ++j) {
                    acc[i][j] = MFMA16(ah[i],  bh4[j], acc[i][j]);
                    acc[i][j] = MFMA16(ah[i],  bl4[j], acc[i][j]);
                    acc[i][j] = MFMA16(al4[i], bh4[j], acc[i][j]);
                }
        }
    }

    float* cb = p.C[sel];
    const int m0 = by * 128 + wm * 64 + kgrp * 4;
    const int n0 = nloc + wn * 64 + l15;
#pragma unroll
    for (int i = 0; i < 4; ++i)
#pragma unroll
        for (int t = 0; t < 4; ++t) {
            float* cp = cb + (size_t)(m0 + i * 16 + t) * ldc + n0;
#pragma unroll
            for (int j = 0; j < 4; ++j) cp[j * 16] = acc[i][j][t];
        }
}

// ---------------------------------------------------------------------------
// Generic fp32 SGEMM (g1@Wf2 and fallback).
// ---------------------------------------------------------------------------
#define GBM 128
#define GBN 128
#define GBK 16

__launch_bounds__(256)
__global__ void sgemm128(const float* __restrict__ A, const float* __restrict__ B,
                         float* __restrict__ C, int M, int N, int K) {
    __shared__ float As[GBK][GBM + 4];
    __shared__ float Bs[GBK][GBN + 4];

    const int tid = threadIdx.x;
    const int bm = blockIdx.y * GBM;
    const int bn = blockIdx.x * GBN;

    const int arow = tid >> 2;
    const int acol = (tid & 3) << 2;
    const int brow = tid >> 5;
    const int bcol = (tid & 31) << 2;
    const int ty = tid >> 4;
    const int tx = tid & 15;

    float acc[8][8];
#pragma unroll
    for (int i = 0; i < 8; ++i)
#pragma unroll
        for (int j = 0; j < 8; ++j) acc[i][j] = 0.f;

    for (int k0 = 0; k0 < K; k0 += GBK) {
#pragma unroll
        for (int r = 0; r < 2; ++r) {
            const int m = arow + r * 64;
            const float4 av = *(const float4*)(A + (size_t)(bm + m) * K + k0 + acol);
            As[acol + 0][m] = av.x;
            As[acol + 1][m] = av.y;
            As[acol + 2][m] = av.z;
            As[acol + 3][m] = av.w;
        }
#pragma unroll
        for (int r = 0; r < 2; ++r) {
            const int kk = brow + r * 8;
            *(float4*)(&Bs[kk][bcol]) =
                *(const float4*)(B + (size_t)(k0 + kk) * N + bn + bcol);
        }
        __syncthreads();

#pragma unroll
        for (int kk = 0; kk < GBK; ++kk) {
            float a[8], bf[8];
#pragma unroll
            for (int i = 0; i < 8; ++i) a[i] = As[kk][ty * 8 + i];
#pragma unroll
            for (int j = 0; j < 8; ++j) bf[j] = Bs[kk][tx * 8 + j];
#pragma unroll
            for (int i = 0; i < 8; ++i)
#pragma unroll
                for (int j = 0; j < 8; ++j)
                    acc[i][j] = fmaf(a[i], bf[j], acc[i][j]);
        }
        __syncthreads();
    }

#pragma unroll
    for (int i = 0; i < 8; ++i) {
        float* cp = C + (size_t)(bm + ty * 8 + i) * N + bn + tx * 8;
        *(float4*)(cp + 0) = make_float4(acc[i][0], acc[i][1], acc[i][2], acc[i][3]);
        *(float4*)(cp + 4) = make_float4(acc[i][4], acc[i][5], acc[i][6], acc[i][7]);
    }
}

// ---------------------------------------------------------------------------
// conv + silu (+ l2norm), 3-in-1 and single variants.
// ---------------------------------------------------------------------------
struct ConvArgs {
    const float* pre[3]; const float* w[3]; float* out[3];
    float scale[3]; int do_norm[3];
};
__global__ void conv_silu_norm3(ConvArgs p) {
    const int z = blockIdx.y;
    const float* __restrict__ pre = p.pre[z];
    const float* __restrict__ wv = p.w[z];
    float* __restrict__ out = p.out[z];
    const float scale = p.scale[z];
    const int do_norm = p.do_norm[z];

    const int blk = blockIdx.x;
    const int h = blk & 15;
    const int bt = blk >> 4;
    const int t = bt & (TT - 1);
    const int b = bt >> 10;
    const int dk = threadIdx.x;
    const int c = h * 128 + dk;

    const size_t off = ((size_t)(b * TT + t)) * DD + c;
    float acc = 0.f;
#pragma unroll
    for (int j = 0; j < 4; ++j) {
        const int tt = t - 3 + j;
        const float x = (tt >= 0) ? pre[off + (size_t)(j - 3) * DD] : 0.f;
        acc = fmaf(x, wv[c * 4 + j], acc);
    }
    float x = acc / (1.f + expf(-acc));

    if (do_norm) {
        float ss = x * x;
#pragma unroll
        for (int s = 1; s < 64; s <<= 1) ss += __shfl_xor(ss, s, 64);
        __shared__ float red[2];
        if ((threadIdx.x & 63) == 0) red[threadIdx.x >> 6] = ss;
        __syncthreads();
        const float tot = red[0] + red[1];
        x = x * rsqrtf(tot + 1e-6f) * scale;
    }
    out[off] = x;
}

__global__ void conv_silu_norm(const float* __restrict__ pre, const float* __restrict__ w,
                               float* __restrict__ out, float scale, int do_norm) {
    const int blk = blockIdx.x;
    const int h = blk & 15;
    const int bt = blk >> 4;
    const int t = bt & (TT - 1);
    const int b = bt >> 10;
    const int dk = threadIdx.x;
    const int c = h * 128 + dk;

    const size_t off = ((size_t)(b * TT + t)) * DD + c;
    float acc = 0.f;
#pragma unroll
    for (int j = 0; j < 4; ++j) {
        const int tt = t - 3 + j;
        const float x = (tt >= 0) ? pre[off + (size_t)(j - 3) * DD] : 0.f;
        acc = fmaf(x, w[c * 4 + j], acc);
    }
    float x = acc / (1.f + expf(-acc));

    if (do_norm) {
        float ss = x * x;
#pragma unroll
        for (int s = 1; s < 64; s <<= 1) ss += __shfl_xor(ss, s, 64);
        __shared__ float red[2];
        if ((threadIdx.x & 63) == 0) red[threadIdx.x >> 6] = ss;
        __syncthreads();
        const float tot = red[0] + red[1];
        x = x * rsqrtf(tot + 1e-6f) * scale;
    }
    out[off] = x;
}

// ---------------------------------------------------------------------------
__global__ void beta_kernel(const float* __restrict__ hid, const float* __restrict__ Wb,
                            float* __restrict__ beta) {
    const int m = blockIdx.x;
    const int t = threadIdx.x;
    const int h = t & 15;
    const int sl = t >> 4;

    const float* hp = hid + (size_t)m * DD + sl * 128;
    const float* wp = Wb + (size_t)sl * 128 * HH + h;
    float p = 0.f;
#pragma unroll 8
    for (int i = 0; i < 128; ++i) p = fmaf(hp[i], wp[i * HH], p);

    __shared__ float red[256];
    red[t] = p;
    __syncthreads();
    if (t < HH) {
        float s = 0.f;
#pragma unroll
        for (int i = 0; i < 16; ++i) s += red[i * 16 + t];
        beta[(size_t)m * HH + t] = 1.f / (1.f + expf(-s));
    }
}

// ---------------------------------------------------------------------------
// decay (fallback layout [b,t,h,g]): d values
// ---------------------------------------------------------------------------
__global__ void decay_kernel(const float* __restrict__ g2, const float* __restrict__ A_log,
                             const float* __restrict__ dt_bias, float* __restrict__ decay) {
    const int idx = blockIdx.x * 256 + threadIdx.x;
    const int g = idx & (NG - 1);
    const int h = (idx >> 3) & (HH - 1);
    const float x = g2[idx] + dt_bias[h * NG + g];
    const float sp = (x > 20.f) ? x : log1pf(expf(x));
    decay[idx] = expf(-expf(A_log[h]) * sp);
}

// ---------------------------------------------------------------------------
// LOG-decay, t-tiled [bh][tblk][g][8]
// ---------------------------------------------------------------------------
__global__ void ldecay_kernel_t(const float* __restrict__ g2, const float* __restrict__ A_log,
                                const float* __restrict__ dt_bias, float* __restrict__ ldtr) {
    const int idx = blockIdx.x * 256 + threadIdx.x;   // (b,t,h,g)
    const int g = idx & 7, h = (idx >> 3) & 15;
    const int t = (idx >> 7) & 1023, b = idx >> 17;
    const float x = g2[idx] + dt_bias[h * NG + g];
    const float sp = (x > 20.f) ? x : log1pf(expf(x));
    const float ld = -expf(A_log[h]) * sp;
    const int bh = b * 16 + h, tblk = t >> 3, tj = t & 7;
    ldtr[((size_t)(bh * 128 + tblk)) * 64 + g * 8 + tj] = ld;
}

// ---------------------------------------------------------------------------
// prep_kernel: per (bh, chunk) tile, fully parallel (2048 blocks).
// Outputs pre-split bf16 N, Aq, Kdec and wexpg LUT (verified round 15).
// ---------------------------------------------------------------------------
__launch_bounds__(256)
__global__ void prep_kernel(const float* __restrict__ kt_g, const float* __restrict__ qt_g,
                            const float* __restrict__ ldec, const float* __restrict__ beta,
                            unsigned short* __restrict__ Nh, unsigned short* __restrict__ Nl,
                            unsigned short* __restrict__ Aqh, unsigned short* __restrict__ Aql,
                            unsigned short* __restrict__ Kdh, unsigned short* __restrict__ Kdl,
                            float* __restrict__ wexpg) {
    __shared__ float kt2[128][17];
    __shared__ float qt2[128][17];
    __shared__ float scr0[4][16][17];
    __shared__ float scr1[4][16][17];
    __shared__ float Am[16][21];
    __shared__ float Nm[16][21];
    __shared__ float ld16[16][8];
    __shared__ float Lc[17][8];
    __shared__ float fctl[16][9];
    __shared__ float betas[16];

    const int bid = blockIdx.x;          // bh*64 + ch
    const int bh = bid >> 6, ch = bid & 63;
    const int b = bh >> 4, h = bh & 15;
    const int tid = threadIdx.x;
    const int w = tid >> 6, lane = tid & 63, l15 = lane & 15, lk = lane >> 4;
    const int tb0 = ch * 2, t0 = ch * 16;
    const size_t kbase = (size_t)bh * 131072;
    const size_t tile = (size_t)bid;

    {
        const int c = tid & 127, half = tid >> 7;
        const float* srk = kt_g + kbase + (size_t)(tb0 + half) * 1024 + c * 8;
        float4 a0 = *(const float4*)(srk);
        float4 a1 = *(const float4*)(srk + 4);
        kt2[c][half * 8 + 0] = a0.x; kt2[c][half * 8 + 1] = a0.y;
        kt2[c][half * 8 + 2] = a0.z; kt2[c][half * 8 + 3] = a0.w;
        kt2[c][half * 8 + 4] = a1.x; kt2[c][half * 8 + 5] = a1.y;
        kt2[c][half * 8 + 6] = a1.z; kt2[c][half * 8 + 7] = a1.w;
        const float* srq = qt_g + kbase + (size_t)(tb0 + half) * 1024 + c * 8;
        a0 = *(const float4*)(srq);
        a1 = *(const float4*)(srq + 4);
        qt2[c][half * 8 + 0] = a0.x; qt2[c][half * 8 + 1] = a0.y;
        qt2[c][half * 8 + 2] = a0.z; qt2[c][half * 8 + 3] = a0.w;
        qt2[c][half * 8 + 4] = a1.x; qt2[c][half * 8 + 5] = a1.y;
        qt2[c][half * 8 + 6] = a1.z; qt2[c][half * 8 + 7] = a1.w;
        if (tid < 128) {
            const int t = tid >> 3, g = tid & 7;
            ld16[t][g] = ldec[(size_t)bh * 8192 + (size_t)(tb0 + (t >> 3)) * 64 + g * 8 + (t & 7)];
        }
        if (tid < 16) betas[tid] = beta[((size_t)b * 1024 + t0 + tid) * 16 + h];
    }
    __syncthreads();
    if (tid < 8) {
        float run = 0.f;
        Lc[0][tid] = 0.f;
#pragma unroll
        for (int j = 0; j < 16; ++j) { run += ld16[j][tid]; Lc[j + 1][tid] = run; }
    }
    __syncthreads();

    float apart[4] = {0.f, 0.f, 0.f, 0.f};
    float aqpart[4] = {0.f, 0.f, 0.f, 0.f};
#pragma unroll
    for (int gi = 0; gi < 2; ++gi) {
        const int g = 2 * w + gi;
        float kv[8], qv[8];
        if (lk < 2) {
#pragma unroll
            for (int j = 0; j < 8; ++j) {
                kv[j] = kt2[g * 16 + lk * 8 + j][l15];
                qv[j] = qt2[g * 16 + lk * 8 + j][l15];
            }
        } else {
#pragma unroll
            for (int j = 0; j < 8; ++j) { kv[j] = 0.f; qv[j] = 0.f; }
        }
        bf16x8 kh, kl2, qh2, ql2;
        split8arr(kv, kh, kl2);
        split8arr(qv, qh2, ql2);
        f32x4 gk = (f32x4){0.f, 0.f, 0.f, 0.f};
        f32x4 gq = (f32x4){0.f, 0.f, 0.f, 0.f};
        gk = MFMA16(kh, kh, gk); gk = MFMA16(kh, kl2, gk); gk = MFMA16(kl2, kh, gk);
        gq = MFMA16(qh2, kh, gq); gq = MFMA16(qh2, kl2, gq); gq = MFMA16(ql2, kh, gq);
#pragma unroll
        for (int j = 0; j < 4; ++j) {
            const int t = lk * 4 + j, r = l15;
            const float f = expf(Lc[t + 1][g] - Lc[r + 1][g]);
            apart[j] = fmaf(f, gk[j], apart[j]);
            aqpart[j] = fmaf(f, gq[j], aqpart[j]);
        }
    }
#pragma unroll
    for (int j = 0; j < 4; ++j) {
        scr0[w][lk * 4 + j][l15] = apart[j];
        scr1[w][lk * 4 + j][l15] = aqpart[j];
    }
    __syncthreads();

    {
        const int t = tid >> 4, r = tid & 15;
        const float sa = scr0[0][t][r] + scr0[1][t][r] + scr0[2][t][r] + scr0[3][t][r];
        const float sq = scr1[0][t][r] + scr1[1][t][r] + scr1[2][t][r] + scr1[3][t][r];
        Am[t][r] = (r < t) ? sa : 0.f;
        const float aqm = (r <= t) ? sq : 0.f;
        unsigned short hh, ll;
        bsplit(aqm, hh, ll);
        Aqh[tile * 256 + t * 16 + r] = hh;
        Aql[tile * 256 + t * 16 + r] = ll;
    }
    __syncthreads();

    if (tid < 16) {
        const int col = tid;
        float x[16];
#pragma unroll
        for (int t = 0; t < 16; ++t) {
            float acc = (t == col) ? betas[col] : 0.f;
#pragma unroll
            for (int r = 0; r < 16; ++r)
                if (r < t) acc = fmaf(-betas[t] * Am[t][r], x[r], acc);
            x[t] = acc;
        }
#pragma unroll
        for (int t = 0; t < 16; ++t) Nm[t][col] = x[t];
    } else if (tid >= 128) {
        const int u = tid - 128;
        const int t = u >> 3, g = u & 7;
        wexpg[tile * 128 + u] = expf(Lc[t + 1][g]);
        fctl[t][g] = expf(Lc[16][g] - Lc[t + 1][g]);
    }
    __syncthreads();

    {
        const int t = tid >> 4, r = tid & 15;
        unsigned short hh, ll;
        bsplit(Nm[t][r], hh, ll);
        Nh[tile * 256 + t * 16 + r] = hh;
        Nl[tile * 256 + t * 16 + r] = ll;
    }
    {
        const int c = tid >> 1, t0e = (tid & 1) * 8;
        const int g = c >> 4;
        float vals[8];
#pragma unroll
        for (int j = 0; j < 8; ++j) vals[j] = kt2[c][t0e + j] * fctl[t0e + j][g];
        bf16x8 hi, lo;
        split8arr(vals, hi, lo);
        *(bf16x8*)(Kdh + tile * 2048 + c * 16 + t0e) = hi;
        *(bf16x8*)(Kdl + tile * 2048 + c * 16 + t0e) = lo;
    }
}

// ---------------------------------------------------------------------------
// Serial chunked recurrence, v3 (verified round 21 best): single barrier per
// chunk, double-buffered vb/scr, full register prefetch of next-chunk
// operands. 256 blocks (v4 slice-split regressed: VALU work is
// column-independent -> 2 blocks/CU doubled VALU per CU).
// ---------------------------------------------------------------------------
__launch_bounds__(256)
__global__ void chunk_recur(const float* __restrict__ qt_g, const float* __restrict__ kt_g,
                            const float* __restrict__ vt_g,
                            const unsigned short* __restrict__ Nh, const unsigned short* __restrict__ Nl,
                            const unsigned short* __restrict__ Aqh, const unsigned short* __restrict__ Aql,
                            const unsigned short* __restrict__ Kdh, const unsigned short* __restrict__ Kdl,
                            const float* __restrict__ wexpg, float* __restrict__ o) {
    __shared__ float Sl[128][17];
    __shared__ float scr0[2][4][16][17];
    __shared__ float scr1[2][4][16][17];
    __shared__ float vb[2][16][17];
    __shared__ float xb4[4][16][17];
    __shared__ float dl4[4][16][17];

    const int bid = blockIdx.x;
    const int xcd = bid & 7, rr = bid >> 3;
    const int bh = xcd * 4 + (rr >> 3);
    const int slice = rr & 7;
    const int b = bh >> 4, h = bh & 15;
    const int tid = threadIdx.x;
    const int w = tid >> 6, lane = tid & 63, l15 = lane & 15, lk = lane >> 4;
    const size_t kbase = (size_t)bh * 131072;
    const size_t obase = ((size_t)b * 1024 * 16 + h) * 128;
    const int cq = w * 32 + lk * 8;
    const int gq2 = cq >> 4;
    const int tv = tid >> 4, u = tid & 15;

    for (int i = tid; i < 128 * 17; i += 256) ((float*)Sl)[i] = 0.f;
    __syncthreads();

    // prefetch ALL operands for chunk 0
    float kr[8], qr[8], vr, ex;
    bf16x8 nhR = zero8(), nlR = zero8(), ahR = zero8(), alR = zero8();
    bf16x8 kdh0 = zero8(), kdl0 = zero8(), kdh1 = zero8(), kdl1 = zero8();
    float w16R0, w16R1;
    {
        const size_t tile0 = (size_t)(bh * 64);
        const size_t rb = kbase + (size_t)(l15 >> 3) * 1024 + (size_t)(l15 & 7);
#pragma unroll
        for (int j = 0; j < 8; ++j) {
            kr[j] = kt_g[rb + (size_t)(cq + j) * 8];
            qr[j] = qt_g[rb + (size_t)(cq + j) * 8];
        }
        vr = vt_g[kbase + (size_t)(tv >> 3) * 1024 + (size_t)(slice * 16 + u) * 8 + (tv & 7)];
        ex = wexpg[tile0 * 128 + l15 * 8 + gq2];
        if (lk < 2) {
            nhR = *(const bf16x8*)(Nh + tile0 * 256 + l15 * 16 + lk * 8);
            nlR = *(const bf16x8*)(Nl + tile0 * 256 + l15 * 16 + lk * 8);
            ahR = *(const bf16x8*)(Aqh + tile0 * 256 + l15 * 16 + lk * 8);
            alR = *(const bf16x8*)(Aql + tile0 * 256 + l15 * 16 + lk * 8);
            kdh0 = *(const bf16x8*)(Kdh + tile0 * 2048 + (size_t)((w * 2 + 0) * 16 + l15) * 16 + lk * 8);
            kdl0 = *(const bf16x8*)(Kdl + tile0 * 2048 + (size_t)((w * 2 + 0) * 16 + l15) * 16 + lk * 8);
            kdh1 = *(const bf16x8*)(Kdh + tile0 * 2048 + (size_t)((w * 2 + 1) * 16 + l15) * 16 + lk * 8);
            kdl1 = *(const bf16x8*)(Kdl + tile0 * 2048 + (size_t)((w * 2 + 1) * 16 + l15) * 16 + lk * 8);
        }
        w16R0 = wexpg[tile0 * 128 + 120 + w * 2 + 0];
        w16R1 = wexpg[tile0 * 128 + 120 + w * 2 + 1];
    }

    for (int ch = 0; ch < 64; ++ch) {
        const int cur = ch & 1;
        const int cn = (ch + 1 < 64) ? (ch + 1) : ch;
        const size_t tilen = (size_t)(bh * 64 + cn);

        // stage v for current chunk (double-buffered)
        vb[cur][tv][u] = vr;

        // ---- phase A: E0/Oq partials from registers ----
        {
            float kv[8], qv[8], sv[8];
#pragma unroll
            for (int j = 0; j < 8; ++j) {
                kv[j] = kr[j] * ex;
                qv[j] = qr[j] * ex;
                sv[j] = Sl[cq + j][l15];
            }
            bf16x8 wh, wl, qh, ql, sh, sl2;
            split8arr(kv, wh, wl);
            split8arr(qv, qh, ql);
            split8arr(sv, sh, sl2);
            f32x4 e0 = (f32x4){0.f, 0.f, 0.f, 0.f};
            f32x4 oq = (f32x4){0.f, 0.f, 0.f, 0.f};
            e0 = MFMA16(wh, sh, e0); e0 = MFMA16(wh, sl2, e0); e0 = MFMA16(wl, sh, e0);
            oq = MFMA16(qh, sh, oq); oq = MFMA16(qh, sl2, oq); oq = MFMA16(ql, sh, oq);
#pragma unroll
            for (int j = 0; j < 4; ++j) {
                scr0[cur][w][lk * 4 + j][l15] = e0[j];
                scr1[cur][w][lk * 4 + j][l15] = oq[j];
            }
        }

        // ---- prefetch next chunk k/q/v/ex (clamped) ----
        {
            const size_t gb2 = kbase + (size_t)(cn * 2) * 1024;
            const size_t rb2 = gb2 + (size_t)(l15 >> 3) * 1024 + (size_t)(l15 & 7);
#pragma unroll
            for (int j = 0; j < 8; ++j) {
                kr[j] = kt_g[rb2 + (size_t)(cq + j) * 8];
                qr[j] = qt_g[rb2 + (size_t)(cq + j) * 8];
            }
            vr = vt_g[gb2 + (size_t)(tv >> 3) * 1024 + (size_t)(slice * 16 + u) * 8 + (tv & 7)];
            ex = wexpg[tilen * 128 + l15 * 8 + gq2];
        }

        __syncthreads();   // the ONLY barrier per chunk

        // ---- phase B (all waves redundant): x = v - sum(E0); d = N@x ----
        bf16x8 dh2, dl2;
        {
            const int tt = lane >> 2, v0 = (lane & 3) * 4;
#pragma unroll
            for (int uu = 0; uu < 4; ++uu) {
                const int v = v0 + uu;
                xb4[w][tt][v] = vb[cur][tt][v] -
                    (scr0[cur][0][tt][v] + scr0[cur][1][tt][v] +
                     scr0[cur][2][tt][v] + scr0[cur][3][tt][v]);
            }
            float xv[8];
            if (lk < 2) {
#pragma unroll
                for (int j = 0; j < 8; ++j) xv[j] = xb4[w][lk * 8 + j][l15];
            } else {
#pragma unroll
                for (int j = 0; j < 8; ++j) xv[j] = 0.f;
            }
            bf16x8 xh, xl;
            split8arr(xv, xh, xl);
            f32x4 d = (f32x4){0.f, 0.f, 0.f, 0.f};
            d = MFMA16(nhR, xh, d); d = MFMA16(nhR, xl, d); d = MFMA16(nlR, xh, d);
#pragma unroll
            for (int j = 0; j < 4; ++j) dl4[w][lk * 4 + j][l15] = d[j];

            float dv[8];
            if (lk < 2) {
#pragma unroll
                for (int j = 0; j < 8; ++j) dv[j] = dl4[w][lk * 8 + j][l15];
            } else {
#pragma unroll
                for (int j = 0; j < 8; ++j) dv[j] = 0.f;
            }
            split8arr(dv, dh2, dl2);

            // o output (wave 0 only)
            if (w == 0) {
                f32x4 oc;
#pragma unroll
                for (int j = 0; j < 4; ++j) {
                    const int t = lk * 4 + j;
                    oc[j] = scr1[cur][0][t][l15] + scr1[cur][1][t][l15] +
                            scr1[cur][2][t][l15] + scr1[cur][3][t][l15];
                }
                oc = MFMA16(ahR, dh2, oc); oc = MFMA16(ahR, dl2, oc); oc = MFMA16(alR, dh2, oc);
#pragma unroll
                for (int j = 0; j < 4; ++j)
                    o[obase + (size_t)(ch * 16 + lk * 4 + j) * 2048 + slice * 16 + l15] = oc[j];
            }
        }

        // ---- prefetch next N/Aq (consumed; safe to overwrite) ----
        if (lk < 2) {
            nhR = *(const bf16x8*)(Nh + tilen * 256 + l15 * 16 + lk * 8);
            nlR = *(const bf16x8*)(Nl + tilen * 256 + l15 * 16 + lk * 8);
            ahR = *(const bf16x8*)(Aqh + tilen * 256 + l15 * 16 + lk * 8);
            alR = *(const bf16x8*)(Aql + tilen * 256 + l15 * 16 + lk * 8);
        }

        // ---- phase C: S update (own rows; operands in registers) ----
        {
            f32x4 sc;
#pragma unroll
            for (int j = 0; j < 4; ++j) sc[j] = Sl[(w * 2 + 0) * 16 + lk * 4 + j][l15] * w16R0;
            sc = MFMA16(kdh0, dh2, sc); sc = MFMA16(kdh0, dl2, sc); sc = MFMA16(kdl0, dh2, sc);
#pragma unroll
            for (int j = 0; j < 4; ++j) Sl[(w * 2 + 0) * 16 + lk * 4 + j][l15] = sc[j];

            f32x4 sc1;
#pragma unroll
            for (int j = 0; j < 4; ++j) sc1[j] = Sl[(w * 2 + 1) * 16 + lk * 4 + j][l15] * w16R1;
            sc1 = MFMA16(kdh1, dh2, sc1); sc1 = MFMA16(kdh1, dl2, sc1); sc1 = MFMA16(kdl1, dh2, sc1);
#pragma unroll
            for (int j = 0; j < 4; ++j) Sl[(w * 2 + 1) * 16 + lk * 4 + j][l15] = sc1[j];
        }

        // ---- prefetch next Kd/w16 (consumed; safe to overwrite) ----
        if (lk < 2) {
            kdh0 = *(const bf16x8*)(Kdh + tilen * 2048 + (size_t)((w * 2 + 0) * 16 + l15) * 16 + lk * 8);
            kdl0 = *(const bf16x8*)(Kdl + tilen * 2048 + (size_t)((w * 2 + 0) * 16 + l15) * 16 + lk * 8);
            kdh1 = *(const bf16x8*)(Kdh + tilen * 2048 + (size_t)((w * 2 + 1) * 16 + l15) * 16 + lk * 8);
            kdl1 = *(const bf16x8*)(Kdl + tilen * 2048 + (size_t)((w * 2 + 1) * 16 + l15) * 16 + lk * 8);
        }
        w16R0 = wexpg[tilen * 128 + 120 + w * 2 + 0];
        w16R1 = wexpg[tilen * 128 + 120 + w * 2 + 1];
    }
}

// ---------------------------------------------------------------------------
// Old-layout recurrence (fallback path only).
// ---------------------------------------------------------------------------
__launch_bounds__(256, 4)
__global__ void recur_kernel(const float* __restrict__ q, const float* __restrict__ k,
                             const float* __restrict__ vv, const float* __restrict__ decay,
                             const float* __restrict__ beta, float* __restrict__ o) {
    const int blk = blockIdx.x;
    const int vblk = blk & 31;
    const int bh = blk >> 5;
    const int b = bh >> 4, h = bh & 15;
    const int w = threadIdx.x >> 6;
    const int lane = threadIdx.x & 63;
    const int vi = vblk * 4 + w;

    float S0 = 0.f, S1 = 0.f;
    const size_t strideT = (size_t)HH * DV;
    const size_t strideT2 = strideT >> 1;
    const size_t base = ((size_t)b * TT * HH + h) * DV;

    const float2* kp = (const float2*)(k + base) + lane;
    const float2* qp = (const float2*)(q + base) + lane;
    const float* vp = vv + base + vi;
    const float* bp = beta + (size_t)b * TT * HH + h;
    const float* dp = decay + ((size_t)b * TT * HH + h) * NG + (lane >> 3);

    float2 kv = kp[0], qv = qp[0];
    float vtv = vp[0], bt = bp[0], dt = dp[0];

    for (int t = 0; t < TT; ++t) {
        const float2 kc = kv, qc = qv;
        const float vc = vtv, bc = bt, dc = dt;

        const int tn = (t + 1 < TT) ? (t + 1) : t;
        kv = kp[(size_t)tn * strideT2];
        qv = qp[(size_t)tn * strideT2];
        vtv = vp[(size_t)tn * strideT];
        bt = bp[(size_t)tn * HH];
        dt = dp[(size_t)tn * HH * NG];

        S0 *= dc;
        S1 *= dc;
        float e = fmaf(kc.x, S0, kc.y * S1);
        e = dpp_sum64(e);
        const float err = readlanef(e, 63);
        const float delta = bc * (vc - err);
        S0 = fmaf(kc.x, delta, S0);
        S1 = fmaf(kc.y, delta, S1);
        float oo = fmaf(qc.x, S0, qc.y * S1);
        oo = dpp_sum64(oo);
        if (lane == 63) o[base + (size_t)t * strideT + vi] = oo;
    }
}

// ---------------------------------------------------------------------------
// Gated RMSNorm -> fp32 y (fallback)
// ---------------------------------------------------------------------------
__global__ void gated_rmsnorm(const float* __restrict__ o,
                              const float* __restrict__ gpre, const float* __restrict__ bg,
                              const float* __restrict__ norm_w, float* __restrict__ y) {
    const int blk = blockIdx.x;
    const int h = blk & 15;
    const int dv = threadIdx.x;
    const size_t off = (size_t)blk * DV + dv;

    const float ov = o[off];
    const float g = gpre[off] + bg[h * 128 + dv];
    const float yv = ov * (g / (1.f + expf(-g)));

    float ss = yv * yv;
#pragma unroll
    for (int s = 1; s < 64; s <<= 1) ss += __shfl_xor(ss, s, 64);
    __shared__ float red[2];
    if ((threadIdx.x & 63) == 0) red[threadIdx.x >> 6] = ss;
    __syncthreads();
    const float mean = (red[0] + red[1]) * (1.f / 128.f);
    y[off] = yv * rsqrtf(mean + 1e-5f) * norm_w[dv];
}

// ---------------------------------------------------------------------------
// Gated RMSNorm -> bf16 hi/lo split y
// ---------------------------------------------------------------------------
__global__ void gated_rmsnorm_split(const float* __restrict__ o,
                                    const float* __restrict__ gpre, const float* __restrict__ bg,
                                    const float* __restrict__ norm_w,
                                    unsigned short* __restrict__ yh,
                                    unsigned short* __restrict__ yl) {
    const int blk = blockIdx.x;
    const int h = blk & 15;
    const int dv = threadIdx.x;
    const size_t off = (size_t)blk * DV + dv;

    const float ov = o[off];
    const float g = gpre[off] + bg[h * 128 + dv];
    const float yv = ov * (g / (1.f + expf(-g)));

    float ss = yv * yv;
#pragma unroll
    for (int s = 1; s < 64; s <<= 1) ss += __shfl_xor(ss, s, 64);
    __shared__ float red[2];
    if ((threadIdx.x & 63) == 0) red[threadIdx.x >> 6] = ss;
    __syncthreads();
    const float mean = (red[0] + red[1]) * (1.f / 128.f);
    const float y = yv * rsqrtf(mean + 1e-5f) * norm_w[dv];
    unsigned short hh, ll;
    bsplit(y, hh, ll);
    yh[off] = hh;
    yl[off] = ll;
}

// ---------------------------------------------------------------------------
extern "C" void kernel_launch(void* const* d_in, const int* in_sizes, int n_in,
                              void* d_out, int out_size, void* d_ws, size_t ws_size,
                              hipStream_t stream) {
    const float* hid    = (const float*)d_in[0];
    const float* Wq     = (const float*)d_in[1];
    const float* Wk     = (const float*)d_in[2];
    const float* Wv     = (const float*)d_in[3];
    const float* conv_q = (const float*)d_in[4];
    const float* conv_k = (const float*)d_in[5];
    const float* conv_v = (const float*)d_in[6];
    const float* Wf1    = (const float*)d_in[7];
    const float* Wf2    = (const float*)d_in[8];
    const float* Wb     = (const float*)d_in[9];
    const float* A_log  = (const float*)d_in[10];
    const float* dt_bias= (const float*)d_in[11];
    const float* Wg     = (const float*)d_in[12];
    const float* bg     = (const float*)d_in[13];
    const float* norm_w = (const float*)d_in[14];
    const float* Wo     = (const float*)d_in[15];
    float* out = (float*)d_out;

    const size_t N1  = (size_t)2048 * 2048;
    const size_t N1B = N1 * 4;
    const int M = BB * TT;

    const size_t NEED_NEW = 9 * N1B + 4390912;

    if (ws_size >= NEED_NEW) {
        // ---------------- MFMA split-precision path ----------------
        char* W = (char*)d_ws;
        unsigned short* hidh = (unsigned short*)W;
        unsigned short* hidl = hidh + N1;
        float* o = (float*)W;
        char* RB = W + N1B;
        unsigned short* Wqth = (unsigned short*)RB;
        unsigned short* Wqtl = Wqth + N1;
        unsigned short* Wkth = Wqtl + N1;
        unsigned short* Wktl = Wkth + N1;
        unsigned short* Wvth = Wktl + N1;
        unsigned short* Wvtl = Wvth + N1;
        unsigned short* Wgth = Wvtl + N1;
        unsigned short* Wgtl = Wgth + N1;
        float* qn = (float*)RB;
        float* kn = qn + N1;
        float* vn = kn + N1;
        unsigned short* Nh  = (unsigned short*)qn;
        unsigned short* Nl  = Nh + 524288;
        unsigned short* Aqh = Nl + 524288;
        unsigned short* Aql = Aqh + 524288;
        float* wexpg = (float*)(Aql + 524288);
        unsigned short* Kdh = (unsigned short*)kn;
        unsigned short* Kdl = Kdh + 4194304;
        char* RC = W + 5 * N1B;
        float* qpre = (float*)RC;
        float* kpre = qpre + N1;
        float* vpre = kpre + N1;
        float* gpre = vpre + N1;
        float* qn_t = qpre;
        float* kn_t = kpre;
        float* vn_t = vpre;
        unsigned short* Woth = (unsigned short*)RC;
        unsigned short* Wotl = Woth + N1;
        unsigned short* yh = (unsigned short*)(RC + N1B);
        unsigned short* yl = yh + N1;
        char* RD = W + 9 * N1B;
        float* g1b   = (float*)RD;
        float* g2b   = g1b + 262144;
        float* betab = g2b + 262144;
        float* ldecb = betab + 32768;
        unsigned short* wf1th = (unsigned short*)(ldecb + 262144);
        unsigned short* wf1tl = wf1th + 262144;

        // 1. splits / transposes
        split_mat<<<1024, 256, 0, stream>>>(hid, hidh, hidl);
        TS4 ts;
        ts.in[0] = Wq; ts.oh[0] = Wqth; ts.ol[0] = Wqtl;
        ts.in[1] = Wk; ts.oh[1] = Wkth; ts.ol[1] = Wktl;
        ts.in[2] = Wv; ts.oh[2] = Wvth; ts.ol[2] = Wvtl;
        ts.in[3] = Wg; ts.oh[3] = Wgth; ts.ol[3] = Wgtl;
        transpose_split4<<<dim3(32, 32, 4), 256, 0, stream>>>(ts);
        transpose_split<<<dim3(2, 32), 256, 0, stream>>>(Wf1, wf1th, wf1tl, 128, 2048);

        // 2. input projections: q/k/v/g PURE BF16 (NM=1, mode 1, grid 64x16),
        //    Wf1 split-3 (NM=3, mode 2, grid 1x16).
        GemmArgs fa;
        fa.Ah = hidh; fa.Al = hidl;
        fa.Bh[0] = Wqth; fa.Bl[0] = Wqtl; fa.C[0] = qpre;
        fa.Bh[1] = Wkth; fa.Bl[1] = Wktl; fa.C[1] = kpre;
        fa.Bh[2] = Wvth; fa.Bl[2] = Wvtl; fa.C[2] = vpre;
        fa.Bh[3] = Wgth; fa.Bl[3] = Wgtl; fa.C[3] = gpre;
        fa.Bh[4] = wf1th; fa.Bl[4] = wf1tl; fa.C[4] = g1b;
        gemm_split<1><<<dim3(64, 16), 256, 0, stream>>>(fa, 1);
        gemm_split<3><<<dim3(1, 16), 256, 0, stream>>>(fa, 2);

        // 3. beta, g2, log-decay (t-tiled)
        beta_kernel<<<M, 256, 0, stream>>>(hid, Wb, betab);
        sgemm128<<<dim3(1, 16), 256, 0, stream>>>(g1b, Wf2, g2b, M, 128, 128);
        ldecay_kernel_t<<<(M * HH * NG) / 256, 256, 0, stream>>>(g2b, A_log, dt_bias, ldecb);

        // 4. conv + silu (+ l2norm)
        ConvArgs ca;
        ca.pre[0] = qpre; ca.w[0] = conv_q; ca.out[0] = qn; ca.scale[0] = SCALE_Q; ca.do_norm[0] = 1;
        ca.pre[1] = kpre; ca.w[1] = conv_k; ca.out[1] = kn; ca.scale[1] = 1.f;     ca.do_norm[1] = 1;
        ca.pre[2] = vpre; ca.w[2] = conv_v; ca.out[2] = vn; ca.scale[2] = 1.f;     ca.do_norm[2] = 0;
        conv_silu_norm3<<<dim3(M * HH, 3), 128, 0, stream>>>(ca);

        // 5. t-tile transpose
        T3 tt;
        tt.in[0] = qn; tt.out[0] = qn_t;
        tt.in[1] = kn; tt.out[1] = kn_t;
        tt.in[2] = vn; tt.out[2] = vn_t;
        transpose_tile3<<<dim3(4096, 3), 256, 0, stream>>>(tt);

        // 6. prep (parallel) + serial chunked recurrence (256 blocks, v3)
        prep_kernel<<<2048, 256, 0, stream>>>(kn_t, qn_t, ldecb, betab,
                                              Nh, Nl, Aqh, Aql, Kdh, Kdl, wexpg);
        chunk_recur<<<256, 256, 0, stream>>>(qn_t, kn_t, vn_t,
                                             Nh, Nl, Aqh, Aql, Kdh, Kdl, wexpg, o);

        // 7. transpose Wo (over dead qn_t)
        transpose_split<<<dim3(32, 32), 256, 0, stream>>>(Wo, Woth, Wotl, 2048, 2048);

        // 8. gated rmsnorm -> y split (over dead kn_t)
        gated_rmsnorm_split<<<M * HH, 128, 0, stream>>>(o, gpre, bg, norm_w, yh, yl);

        // 9. output projection (split-2, NM=2, mode 0)
        GemmArgs oa;
        oa.Ah = yh; oa.Al = yl;
        for (int i = 0; i < 5; ++i) { oa.Bh[i] = Woth; oa.Bl[i] = Wotl; oa.C[i] = out; }
        gemm_split<2><<<dim3(16, 16), 256, 0, stream>>>(oa, 0);
    } else {
        // ---------------- fallback: fp32 path ----------------
        float* ws = (float*)d_ws;
        float* qpre = ws + 0 * N1;
        float* kpre = ws + 1 * N1;
        float* vpre = ws + 2 * N1;
        float* gpre = ws + 3 * N1;
        float* qn   = ws + 4 * N1;
        float* kn   = ws + 5 * N1;
        float* vn   = ws + 6 * N1;
        float* g1b  = ws + 7 * N1;
        float* g2b  = g1b + (size_t)BB * TT * DV;
        float* betab= g2b + (size_t)BB * TT * HH * NG;
        float* decayb = betab + (size_t)BB * TT * HH;
        float* o = qpre;
        float* y = vpre;

        sgemm128<<<dim3(16, 16), 256, 0, stream>>>(hid, Wq, qpre, M, 2048, 2048);
        sgemm128<<<dim3(16, 16), 256, 0, stream>>>(hid, Wk, kpre, M, 2048, 2048);
        sgemm128<<<dim3(16, 16), 256, 0, stream>>>(hid, Wv, vpre, M, 2048, 2048);
        sgemm128<<<dim3(16, 16), 256, 0, stream>>>(hid, Wg, gpre, M, 2048, 2048);
        sgemm128<<<dim3(1, 16), 256, 0, stream>>>(hid, Wf1, g1b, M, 128, 2048);
        sgemm128<<<dim3(1, 16), 256, 0, stream>>>(g1b, Wf2, g2b, M, 128, 128);
        beta_kernel<<<M, 256, 0, stream>>>(hid, Wb, betab);

        conv_silu_norm<<<M * HH, 128, 0, stream>>>(qpre, conv_q, qn, SCALE_Q, 1);
        conv_silu_norm<<<M * HH, 128, 0, stream>>>(kpre, conv_k, kn, 1.f, 1);
        conv_silu_norm<<<M * HH, 128, 0, stream>>>(vpre, conv_v, vn, 1.f, 0);

        decay_kernel<<<(M * HH * NG) / 256, 256, 0, stream>>>(g2b, A_log, dt_bias, decayb);

        recur_kernel<<<BB * HH * (DV / 4), 256, 0, stream>>>(qn, kn, vn, decayb, betab, o);

        gated_rmsnorm<<<M * HH, 128, 0, stream>>>(o, gpre, bg, norm_w, y);

        sgemm128<<<dim3(16, 16), 256, 0, stream>>>(y, Wo, out, M, 2048, 2048);
    }
}

// Round 24
// 446.507 us; speedup vs baseline: 1.1672x; 1.0758x over previous
//
#include <hip/hip_runtime.h>
#include <hip/hip_bf16.h>
#include <math.h>

// Problem constants (fixed by setup_inputs)
#define BB 2
#define TT 1024
#define DD 2048
#define HH 16
#define DK 128
#define DV 128
#define NG 8
#define GG 16
#define SCALE_Q 0.08838834764831845f  // 128^-0.5

typedef __attribute__((ext_vector_type(8))) short bf16x8;
typedef __attribute__((ext_vector_type(4))) float f32x4;
typedef __attribute__((ext_vector_type(4))) unsigned int u32x4;

#define MFMA16(a, b, c) __builtin_amdgcn_mfma_f32_16x16x32_bf16((a), (b), (c), 0, 0, 0)

// bf16 split helpers (RNE)
__device__ __forceinline__ unsigned short f2bf(float v) {
    unsigned u = __float_as_uint(v);
    return (unsigned short)((u + 0x7FFFu + ((u >> 16) & 1u)) >> 16);
}
__device__ __forceinline__ float bf2f(unsigned short h) {
    return __uint_as_float(((unsigned)h) << 16);
}
__device__ __forceinline__ void bsplit(float v, unsigned short& h, unsigned short& l) {
    h = f2bf(v);
    l = f2bf(v - bf2f(h));
}
// Fast pairwise split via v_cvt_pk_bf16_f32 (HW RNE).
__device__ __forceinline__ void split8arr(const float* v, bf16x8& hi, bf16x8& lo) {
    union U { u32x4 u; bf16x8 s; } H, L;
#pragma unroll
    for (int p = 0; p < 4; ++p) {
        const float a = v[2 * p], b = v[2 * p + 1];
        unsigned hpk;
        asm("v_cvt_pk_bf16_f32 %0, %1, %2" : "=v"(hpk) : "v"(a), "v"(b));
        const float ra = __uint_as_float(hpk << 16);
        const float rb = __uint_as_float(hpk & 0xFFFF0000u);
        unsigned lpk;
        asm("v_cvt_pk_bf16_f32 %0, %1, %2" : "=v"(lpk) : "v"(a - ra), "v"(b - rb));
        H.u[p] = hpk;
        L.u[p] = lpk;
    }
    hi = H.s;
    lo = L.s;
}
__device__ __forceinline__ bf16x8 zero8() {
    bf16x8 z;
#pragma unroll
    for (int i = 0; i < 8; ++i) z[i] = 0;
    return z;
}

// ---------------------------------------------------------------------------
// DPP wave64 sum (fallback recurrence only).
// ---------------------------------------------------------------------------
__device__ __forceinline__ float dpp_sum64(float x) {
    x += __int_as_float(__builtin_amdgcn_update_dpp(0, __float_as_int(x), 0x111, 0xf, 0xf, true));
    x += __int_as_float(__builtin_amdgcn_update_dpp(0, __float_as_int(x), 0x112, 0xf, 0xf, true));
    x += __int_as_float(__builtin_amdgcn_update_dpp(0, __float_as_int(x), 0x114, 0xf, 0xf, true));
    x += __int_as_float(__builtin_amdgcn_update_dpp(0, __float_as_int(x), 0x118, 0xf, 0xf, true));
    x += __int_as_float(__builtin_amdgcn_update_dpp(0, __float_as_int(x), 0x142, 0xa, 0xf, false));
    x += __int_as_float(__builtin_amdgcn_update_dpp(0, __float_as_int(x), 0x143, 0xc, 0xf, false));
    return x;
}
__device__ __forceinline__ float readlanef(float x, int l) {
    return __int_as_float(__builtin_amdgcn_readlane(__float_as_int(x), l));
}

// ---------------------------------------------------------------------------
// split: fp32 [n] -> bf16 hi/lo
// ---------------------------------------------------------------------------
__global__ void split_mat(const float* __restrict__ in, unsigned short* __restrict__ oh,
                          unsigned short* __restrict__ ol) {
    const int i0 = (blockIdx.x * 256 + threadIdx.x) * 16;
#pragma unroll
    for (int r = 0; r < 4; ++r) {
        const float4 v = *(const float4*)(in + i0 + r * 4);
        unsigned short h0, l0, h1, l1, h2, l2, h3, l3;
        bsplit(v.x, h0, l0); bsplit(v.y, h1, l1);
        bsplit(v.z, h2, l2); bsplit(v.w, h3, l3);
        short4 hh; hh.x = (short)h0; hh.y = (short)h1; hh.z = (short)h2; hh.w = (short)h3;
        short4 ll; ll.x = (short)l0; ll.y = (short)l1; ll.z = (short)l2; ll.w = (short)l3;
        *(short4*)(oh + i0 + r * 4) = hh;
        *(short4*)(ol + i0 + r * 4) = ll;
    }
}

// ---------------------------------------------------------------------------
// transpose + split: in fp32 [Kin][Nin] -> out bf16 hi/lo [Nin][Kin]
// ---------------------------------------------------------------------------
__device__ __forceinline__ void tsplit_body(const float* __restrict__ in,
                                            unsigned short* __restrict__ oh,
                                            unsigned short* __restrict__ ol,
                                            int Nin, int Kin, int bx, int by, int tid) {
    __shared__ float t[64][65];
    const int c4 = (tid & 15) * 4, r0 = tid >> 4;
#pragma unroll
    for (int rep = 0; rep < 4; ++rep) {
        const int r = r0 + rep * 16;
        const float4 v = *(const float4*)(in + (size_t)(by * 64 + r) * Nin + bx * 64 + c4);
        t[r][c4] = v.x; t[r][c4 + 1] = v.y; t[r][c4 + 2] = v.z; t[r][c4 + 3] = v.w;
    }
    __syncthreads();
#pragma unroll
    for (int rep = 0; rep < 4; ++rep) {
        const int n = r0 + rep * 16;
        short4 hh, ll;
        unsigned short h, l;
        bsplit(t[c4 + 0][n], h, l); hh.x = (short)h; ll.x = (short)l;
        bsplit(t[c4 + 1][n], h, l); hh.y = (short)h; ll.y = (short)l;
        bsplit(t[c4 + 2][n], h, l); hh.z = (short)h; ll.z = (short)l;
        bsplit(t[c4 + 3][n], h, l); hh.w = (short)h; ll.w = (short)l;
        const size_t o = (size_t)(bx * 64 + n) * Kin + by * 64 + c4;
        *(short4*)(oh + o) = hh;
        *(short4*)(ol + o) = ll;
    }
}

__global__ void transpose_split(const float* __restrict__ in, unsigned short* __restrict__ oh,
                                unsigned short* __restrict__ ol, int Nin, int Kin) {
    tsplit_body(in, oh, ol, Nin, Kin, blockIdx.x, blockIdx.y, threadIdx.x);
}

struct TS4 { const float* in[4]; unsigned short* oh[4]; unsigned short* ol[4]; };
__global__ void transpose_split4(TS4 p) {
    const int z = blockIdx.z;
    tsplit_body(p.in[z], p.oh[z], p.ol[z], 2048, 2048, blockIdx.x, blockIdx.y, threadIdx.x);
}

// ---------------------------------------------------------------------------
// FUSED conv + silu (+ l2norm) -> t-tiled output [bh][tblk][c][8].
// Block = (bh, tblk), 128 threads (one per channel). Reduction order per t is
// identical to the old conv kernel (shfl_xor tree + 2-wave combine), so the
// output is bit-identical; the transpose_tile3 pass is eliminated.
// ---------------------------------------------------------------------------
struct CT3 {
    const float* pre[3]; const float* w[3]; float* out[3];
    float scale[3]; int do_norm[3];
};
__global__ void conv_tile3(CT3 p) {
    const int z = blockIdx.y;
    const float* __restrict__ pre = p.pre[z];
    const float* __restrict__ wv = p.w[z];
    float* __restrict__ out = p.out[z];
    const float scale = p.scale[z];
    const int do_norm = p.do_norm[z];

    const int blk = blockIdx.x;           // bh*128 + tblk
    const int bh = blk >> 7, tblk = blk & 127;
    const int b = bh >> 4, h = bh & 15;
    const int c = threadIdx.x;            // channel 0..127
    const int ch = h * 128 + c;
    const int t0 = tblk * 8;

    const float4 wr = *(const float4*)(wv + ch * 4);

    float xv[11];
#pragma unroll
    for (int j = 0; j < 11; ++j) {
        const int t = t0 - 3 + j;
        xv[j] = (t >= 0) ? pre[((size_t)(b * TT + t)) * DD + ch] : 0.f;
    }
    float x[8];
#pragma unroll
    for (int tj = 0; tj < 8; ++tj) {
        float acc = xv[tj] * wr.x;
        acc = fmaf(xv[tj + 1], wr.y, acc);
        acc = fmaf(xv[tj + 2], wr.z, acc);
        acc = fmaf(xv[tj + 3], wr.w, acc);
        x[tj] = acc / (1.f + expf(-acc));
    }
    if (do_norm) {
        __shared__ float red[2][8];
        float ss[8];
#pragma unroll
        for (int tj = 0; tj < 8; ++tj) {
            float s = x[tj] * x[tj];
#pragma unroll
            for (int d = 1; d < 64; d <<= 1) s += __shfl_xor(s, d, 64);
            ss[tj] = s;
        }
        if ((c & 63) == 0) {
#pragma unroll
            for (int tj = 0; tj < 8; ++tj) red[c >> 6][tj] = ss[tj];
        }
        __syncthreads();
#pragma unroll
        for (int tj = 0; tj < 8; ++tj)
            x[tj] = x[tj] * rsqrtf(red[0][tj] + red[1][tj] + 1e-6f) * scale;
    }
    float* op = out + ((size_t)blk * 128 + c) * 8;
    *(float4*)(op)     = make_float4(x[0], x[1], x[2], x[3]);
    *(float4*)(op + 4) = make_float4(x[4], x[5], x[6], x[7]);
}

// ---------------------------------------------------------------------------
// Split-precision bf16 MFMA GEMM, XCD-swizzled, NM = MFMA count (COMPILE-TIME):
//   NM=1: pure bf16 (Ah x Bh), stages 2 arrays  -- fused input projections
//   NM=2: split-2 (Ah x (Bh+Bl)), stages 3      -- output projection
//   NM=3: split-3 (hh+hl+lh), stages 4          -- Wf1 (decay-sensitive)
// mode 0: single output sel0, ldc 2048, nloc = bx*128   (out-proj, grid 16x16)
// mode 1: fused q/k/v/g, grid 64x16, sel = bx>>4        (input projections)
// mode 2: Wf1 single, grid 1x16, sel=4, nloc=0, ldc=128
// ---------------------------------------------------------------------------
struct GemmArgs {
    const unsigned short* Ah; const unsigned short* Al;
    const unsigned short* Bh[5]; const unsigned short* Bl[5];
    float* C[5];
};

#define AHI 0
#define ALO 8192
#define BHI 16384
#define BLO 24576

#define GL2LDS(g, s) __builtin_amdgcn_global_load_lds( \
    (const __attribute__((address_space(1))) void*)(g), \
    (__attribute__((address_space(3))) void*)(s), 16, 0, 0)

template <int NM>
__launch_bounds__(256, 3)
__global__ void gemm_split(GemmArgs p, int mode) {
    __shared__ __attribute__((aligned(16))) char lds[32768];
    const int tid = threadIdx.x;

    // XCD-aware bijective swizzle (gridDim.y == 16 for all launches)
    int bx, by;
    {
        const int gw = gridDim.x;
        const int lin = blockIdx.y * gw + blockIdx.x;
        const int per = (gw * 16) >> 3;
        const int swz = (lin & 7) * per + (lin >> 3);
        bx = swz >> 4;
        by = swz & 15;
    }

    int sel, nloc, ldc;
    if (mode == 1)      { sel = bx >> 4; nloc = (bx & 15) * 128; ldc = 2048; }
    else if (mode == 2) { sel = 4;       nloc = 0;               ldc = 128;  }
    else                { sel = 0;       nloc = bx * 128;        ldc = 2048; }

    const unsigned short* Asrc_h = p.Ah + (size_t)(by * 128) * 2048;
    const unsigned short* Asrc_l = p.Al + (size_t)(by * 128) * 2048;
    const unsigned short* Bsrc_h = p.Bh[sel] + (size_t)nloc * 2048;
    const unsigned short* Bsrc_l = p.Bl[sel] + (size_t)nloc * 2048;

    const int r0 = tid >> 2, ps0 = tid & 3;
    const int r1 = (tid + 256) >> 2, ps1 = tid & 3;
    const size_t ga0 = (size_t)r0 * 2048 + (size_t)((ps0 ^ ((r0 >> 1) & 3)) * 8);
    const size_t ga1 = (size_t)r1 * 2048 + (size_t)((ps1 ^ ((r1 >> 1) & 3)) * 8);
    const int lb0 = (tid & 192) * 16;
    const int lb1 = (256 + (tid & 192)) * 16;

    const int lane = tid & 63;
    const int l15 = lane & 15, kgrp = lane >> 4;
    const int w = tid >> 6, wm = w >> 1, wn = w & 1;
    const int swzf = kgrp ^ ((l15 >> 1) & 3);
    const int fro = l15 * 64 + swzf * 16;
    const int aoff = wm * 4096, boff = wn * 4096;

    f32x4 acc[4][4];
#pragma unroll
    for (int i = 0; i < 4; ++i)
#pragma unroll
        for (int j = 0; j < 4; ++j) acc[i][j] = (f32x4){0.f, 0.f, 0.f, 0.f};

    for (int k0 = 0; k0 < 2048; k0 += 32) {
        __syncthreads();
        GL2LDS(Asrc_h + k0 + ga0, lds + AHI + lb0);
        GL2LDS(Asrc_h + k0 + ga1, lds + AHI + lb1);
        if constexpr (NM >= 3) {
            GL2LDS(Asrc_l + k0 + ga0, lds + ALO + lb0);
            GL2LDS(Asrc_l + k0 + ga1, lds + ALO + lb1);
        }
        GL2LDS(Bsrc_h + k0 + ga0, lds + BHI + lb0);
        GL2LDS(Bsrc_h + k0 + ga1, lds + BHI + lb1);
        if constexpr (NM >= 2) {
            GL2LDS(Bsrc_l + k0 + ga0, lds + BLO + lb0);
            GL2LDS(Bsrc_l + k0 + ga1, lds + BLO + lb1);
        }
        __syncthreads();

        bf16x8 ah[4], bh4[4];
#pragma unroll
        for (int f = 0; f < 4; ++f) {
            ah[f]  = *(const bf16x8*)(lds + AHI + aoff + f * 1024 + fro);
            bh4[f] = *(const bf16x8*)(lds + BHI + boff + f * 1024 + fro);
        }
        if constexpr (NM == 1) {
#pragma unroll
            for (int i = 0; i < 4; ++i)
#pragma unroll
                for (int j = 0; j < 4; ++j)
                    acc[i][j] = MFMA16(ah[i], bh4[j], acc[i][j]);
        } else if constexpr (NM == 2) {
            bf16x8 bl4[4];
#pragma unroll
            for (int f = 0; f < 4; ++f)
                bl4[f] = *(const bf16x8*)(lds + BLO + boff + f * 1024 + fro);
#pragma unroll
            for (int i = 0; i < 4; ++i)
#pragma unroll
                for (int j = 0; j < 4; ++j) {
                    acc[i][j] = MFMA16(ah[i], bh4[j], acc[i][j]);
                    acc[i][j] = MFMA16(ah[i], bl4[j], acc[i][j]);
                }
        } else {
            bf16x8 bl4[4], al4[4];
#pragma unroll
            for (int f = 0; f < 4; ++f) {
                bl4[f] = *(const bf16x8*)(lds + BLO + boff + f * 1024 + fro);
                al4[f] = *(const bf16x8*)(lds + ALO + aoff + f * 1024 + fro);
            }
#pragma unroll
            for (int i = 0; i < 4; ++i)
#pragma unroll
                for (int j = 0; j < 4; ++j) {
                    acc[i][j] = MFMA16(ah[i],  bh4[j], acc[i][j]);
                    acc[i][j] = MFMA16(ah[i],  bl4[j], acc[i][j]);
                    acc[i][j] = MFMA16(al4[i], bh4[j], acc[i][j]);
                }
        }
    }

    float* cb = p.C[sel];
    const int m0 = by * 128 + wm * 64 + kgrp * 4;
    const int n0 = nloc + wn * 64 + l15;
#pragma unroll
    for (int i = 0; i < 4; ++i)
#pragma unroll
        for (int t = 0; t < 4; ++t) {
            float* cp = cb + (size_t)(m0 + i * 16 + t) * ldc + n0;
#pragma unroll
            for (int j = 0; j < 4; ++j) cp[j * 16] = acc[i][j][t];
        }
}

// ---------------------------------------------------------------------------
// Generic fp32 SGEMM (g1@Wf2 and fallback).
// ---------------------------------------------------------------------------
#define GBM 128
#define GBN 128
#define GBK 16

__launch_bounds__(256)
__global__ void sgemm128(const float* __restrict__ A, const float* __restrict__ B,
                         float* __restrict__ C, int M, int N, int K) {
    __shared__ float As[GBK][GBM + 4];
    __shared__ float Bs[GBK][GBN + 4];

    const int tid = threadIdx.x;
    const int bm = blockIdx.y * GBM;
    const int bn = blockIdx.x * GBN;

    const int arow = tid >> 2;
    const int acol = (tid & 3) << 2;
    const int brow = tid >> 5;
    const int bcol = (tid & 31) << 2;
    const int ty = tid >> 4;
    const int tx = tid & 15;

    float acc[8][8];
#pragma unroll
    for (int i = 0; i < 8; ++i)
#pragma unroll
        for (int j = 0; j < 8; ++j) acc[i][j] = 0.f;

    for (int k0 = 0; k0 < K; k0 += GBK) {
#pragma unroll
        for (int r = 0; r < 2; ++r) {
            const int m = arow + r * 64;
            const float4 av = *(const float4*)(A + (size_t)(bm + m) * K + k0 + acol);
            As[acol + 0][m] = av.x;
            As[acol + 1][m] = av.y;
            As[acol + 2][m] = av.z;
            As[acol + 3][m] = av.w;
        }
#pragma unroll
        for (int r = 0; r < 2; ++r) {
            const int kk = brow + r * 8;
            *(float4*)(&Bs[kk][bcol]) =
                *(const float4*)(B + (size_t)(k0 + kk) * N + bn + bcol);
        }
        __syncthreads();

#pragma unroll
        for (int kk = 0; kk < GBK; ++kk) {
            float a[8], bf[8];
#pragma unroll
            for (int i = 0; i < 8; ++i) a[i] = As[kk][ty * 8 + i];
#pragma unroll
            for (int j = 0; j < 8; ++j) bf[j] = Bs[kk][tx * 8 + j];
#pragma unroll
            for (int i = 0; i < 8; ++i)
#pragma unroll
                for (int j = 0; j < 8; ++j)
                    acc[i][j] = fmaf(a[i], bf[j], acc[i][j]);
        }
        __syncthreads();
    }

#pragma unroll
    for (int i = 0; i < 8; ++i) {
        float* cp = C + (size_t)(bm + ty * 8 + i) * N + bn + tx * 8;
        *(float4*)(cp + 0) = make_float4(acc[i][0], acc[i][1], acc[i][2], acc[i][3]);
        *(float4*)(cp + 4) = make_float4(acc[i][4], acc[i][5], acc[i][6], acc[i][7]);
    }
}

// ---------------------------------------------------------------------------
// conv + silu (+ l2norm), single variant (fallback path).
// ---------------------------------------------------------------------------
__global__ void conv_silu_norm(const float* __restrict__ pre, const float* __restrict__ w,
                               float* __restrict__ out, float scale, int do_norm) {
    const int blk = blockIdx.x;
    const int h = blk & 15;
    const int bt = blk >> 4;
    const int t = bt & (TT - 1);
    const int b = bt >> 10;
    const int dk = threadIdx.x;
    const int c = h * 128 + dk;

    const size_t off = ((size_t)(b * TT + t)) * DD + c;
    float acc = 0.f;
#pragma unroll
    for (int j = 0; j < 4; ++j) {
        const int tt = t - 3 + j;
        const float x = (tt >= 0) ? pre[off + (size_t)(j - 3) * DD] : 0.f;
        acc = fmaf(x, w[c * 4 + j], acc);
    }
    float x = acc / (1.f + expf(-acc));

    if (do_norm) {
        float ss = x * x;
#pragma unroll
        for (int s = 1; s < 64; s <<= 1) ss += __shfl_xor(ss, s, 64);
        __shared__ float red[2];
        if ((threadIdx.x & 63) == 0) red[threadIdx.x >> 6] = ss;
        __syncthreads();
        const float tot = red[0] + red[1];
        x = x * rsqrtf(tot + 1e-6f) * scale;
    }
    out[off] = x;
}

// ---------------------------------------------------------------------------
__global__ void beta_kernel(const float* __restrict__ hid, const float* __restrict__ Wb,
                            float* __restrict__ beta) {
    const int m = blockIdx.x;
    const int t = threadIdx.x;
    const int h = t & 15;
    const int sl = t >> 4;

    const float* hp = hid + (size_t)m * DD + sl * 128;
    const float* wp = Wb + (size_t)sl * 128 * HH + h;
    float p = 0.f;
#pragma unroll 8
    for (int i = 0; i < 128; ++i) p = fmaf(hp[i], wp[i * HH], p);

    __shared__ float red[256];
    red[t] = p;
    __syncthreads();
    if (t < HH) {
        float s = 0.f;
#pragma unroll
        for (int i = 0; i < 16; ++i) s += red[i * 16 + t];
        beta[(size_t)m * HH + t] = 1.f / (1.f + expf(-s));
    }
}

// ---------------------------------------------------------------------------
// decay (fallback layout [b,t,h,g]): d values
// ---------------------------------------------------------------------------
__global__ void decay_kernel(const float* __restrict__ g2, const float* __restrict__ A_log,
                             const float* __restrict__ dt_bias, float* __restrict__ decay) {
    const int idx = blockIdx.x * 256 + threadIdx.x;
    const int g = idx & (NG - 1);
    const int h = (idx >> 3) & (HH - 1);
    const float x = g2[idx] + dt_bias[h * NG + g];
    const float sp = (x > 20.f) ? x : log1pf(expf(x));
    decay[idx] = expf(-expf(A_log[h]) * sp);
}

// ---------------------------------------------------------------------------
// LOG-decay, t-tiled [bh][tblk][g][8]
// ---------------------------------------------------------------------------
__global__ void ldecay_kernel_t(const float* __restrict__ g2, const float* __restrict__ A_log,
                                const float* __restrict__ dt_bias, float* __restrict__ ldtr) {
    const int idx = blockIdx.x * 256 + threadIdx.x;   // (b,t,h,g)
    const int g = idx & 7, h = (idx >> 3) & 15;
    const int t = (idx >> 7) & 1023, b = idx >> 17;
    const float x = g2[idx] + dt_bias[h * NG + g];
    const float sp = (x > 20.f) ? x : log1pf(expf(x));
    const float ld = -expf(A_log[h]) * sp;
    const int bh = b * 16 + h, tblk = t >> 3, tj = t & 7;
    ldtr[((size_t)(bh * 128 + tblk)) * 64 + g * 8 + tj] = ld;
}

// ---------------------------------------------------------------------------
// prep_kernel: per (bh, chunk) tile, fully parallel (2048 blocks).
// Outputs pre-split bf16 N, Aq, Kdec and wexpg LUT (verified round 15).
// ---------------------------------------------------------------------------
__launch_bounds__(256)
__global__ void prep_kernel(const float* __restrict__ kt_g, const float* __restrict__ qt_g,
                            const float* __restrict__ ldec, const float* __restrict__ beta,
                            unsigned short* __restrict__ Nh, unsigned short* __restrict__ Nl,
                            unsigned short* __restrict__ Aqh, unsigned short* __restrict__ Aql,
                            unsigned short* __restrict__ Kdh, unsigned short* __restrict__ Kdl,
                            float* __restrict__ wexpg) {
    __shared__ float kt2[128][17];
    __shared__ float qt2[128][17];
    __shared__ float scr0[4][16][17];
    __shared__ float scr1[4][16][17];
    __shared__ float Am[16][21];
    __shared__ float Nm[16][21];
    __shared__ float ld16[16][8];
    __shared__ float Lc[17][8];
    __shared__ float fctl[16][9];
    __shared__ float betas[16];

    const int bid = blockIdx.x;          // bh*64 + ch
    const int bh = bid >> 6, ch = bid & 63;
    const int b = bh >> 4, h = bh & 15;
    const int tid = threadIdx.x;
    const int w = tid >> 6, lane = tid & 63, l15 = lane & 15, lk = lane >> 4;
    const int tb0 = ch * 2, t0 = ch * 16;
    const size_t kbase = (size_t)bh * 131072;
    const size_t tile = (size_t)bid;

    {
        const int c = tid & 127, half = tid >> 7;
        const float* srk = kt_g + kbase + (size_t)(tb0 + half) * 1024 + c * 8;
        float4 a0 = *(const float4*)(srk);
        float4 a1 = *(const float4*)(srk + 4);
        kt2[c][half * 8 + 0] = a0.x; kt2[c][half * 8 + 1] = a0.y;
        kt2[c][half * 8 + 2] = a0.z; kt2[c][half * 8 + 3] = a0.w;
        kt2[c][half * 8 + 4] = a1.x; kt2[c][half * 8 + 5] = a1.y;
        kt2[c][half * 8 + 6] = a1.z; kt2[c][half * 8 + 7] = a1.w;
        const float* srq = qt_g + kbase + (size_t)(tb0 + half) * 1024 + c * 8;
        a0 = *(const float4*)(srq);
        a1 = *(const float4*)(srq + 4);
        qt2[c][half * 8 + 0] = a0.x; qt2[c][half * 8 + 1] = a0.y;
        qt2[c][half * 8 + 2] = a0.z; qt2[c][half * 8 + 3] = a0.w;
        qt2[c][half * 8 + 4] = a1.x; qt2[c][half * 8 + 5] = a1.y;
        qt2[c][half * 8 + 6] = a1.z; qt2[c][half * 8 + 7] = a1.w;
        if (tid < 128) {
            const int t = tid >> 3, g = tid & 7;
            ld16[t][g] = ldec[(size_t)bh * 8192 + (size_t)(tb0 + (t >> 3)) * 64 + g * 8 + (t & 7)];
        }
        if (tid < 16) betas[tid] = beta[((size_t)b * 1024 + t0 + tid) * 16 + h];
    }
    __syncthreads();
    if (tid < 8) {
        float run = 0.f;
        Lc[0][tid] = 0.f;
#pragma unroll
        for (int j = 0; j < 16; ++j) { run += ld16[j][tid]; Lc[j + 1][tid] = run; }
    }
    __syncthreads();

    float apart[4] = {0.f, 0.f, 0.f, 0.f};
    float aqpart[4] = {0.f, 0.f, 0.f, 0.f};
#pragma unroll
    for (int gi = 0; gi < 2; ++gi) {
        const int g = 2 * w + gi;
        float kv[8], qv[8];
        if (lk < 2) {
#pragma unroll
            for (int j = 0; j < 8; ++j) {
                kv[j] = kt2[g * 16 + lk * 8 + j][l15];
                qv[j] = qt2[g * 16 + lk * 8 + j][l15];
            }
        } else {
#pragma unroll
            for (int j = 0; j < 8; ++j) { kv[j] = 0.f; qv[j] = 0.f; }
        }
        bf16x8 kh, kl2, qh2, ql2;
        split8arr(kv, kh, kl2);
        split8arr(qv, qh2, ql2);
        f32x4 gk = (f32x4){0.f, 0.f, 0.f, 0.f};
        f32x4 gq = (f32x4){0.f, 0.f, 0.f, 0.f};
        gk = MFMA16(kh, kh, gk); gk = MFMA16(kh, kl2, gk); gk = MFMA16(kl2, kh, gk);
        gq = MFMA16(qh2, kh, gq); gq = MFMA16(qh2, kl2, gq); gq = MFMA16(ql2, kh, gq);
#pragma unroll
        for (int j = 0; j < 4; ++j) {
            const int t = lk * 4 + j, r = l15;
            const float f = expf(Lc[t + 1][g] - Lc[r + 1][g]);
            apart[j] = fmaf(f, gk[j], apart[j]);
            aqpart[j] = fmaf(f, gq[j], aqpart[j]);
        }
    }
#pragma unroll
    for (int j = 0; j < 4; ++j) {
        scr0[w][lk * 4 + j][l15] = apart[j];
        scr1[w][lk * 4 + j][l15] = aqpart[j];
    }
    __syncthreads();

    {
        const int t = tid >> 4, r = tid & 15;
        const float sa = scr0[0][t][r] + scr0[1][t][r] + scr0[2][t][r] + scr0[3][t][r];
        const float sq = scr1[0][t][r] + scr1[1][t][r] + scr1[2][t][r] + scr1[3][t][r];
        Am[t][r] = (r < t) ? sa : 0.f;
        const float aqm = (r <= t) ? sq : 0.f;
        unsigned short hh, ll;
        bsplit(aqm, hh, ll);
        Aqh[tile * 256 + t * 16 + r] = hh;
        Aql[tile * 256 + t * 16 + r] = ll;
    }
    __syncthreads();

    if (tid < 16) {
        const int col = tid;
        float x[16];
#pragma unroll
        for (int t = 0; t < 16; ++t) {
            float acc = (t == col) ? betas[col] : 0.f;
#pragma unroll
            for (int r = 0; r < 16; ++r)
                if (r < t) acc = fmaf(-betas[t] * Am[t][r], x[r], acc);
            x[t] = acc;
        }
#pragma unroll
        for (int t = 0; t < 16; ++t) Nm[t][col] = x[t];
    } else if (tid >= 128) {
        const int u = tid - 128;
        const int t = u >> 3, g = u & 7;
        wexpg[tile * 128 + u] = expf(Lc[t + 1][g]);
        fctl[t][g] = expf(Lc[16][g] - Lc[t + 1][g]);
    }
    __syncthreads();

    {
        const int t = tid >> 4, r = tid & 15;
        unsigned short hh, ll;
        bsplit(Nm[t][r], hh, ll);
        Nh[tile * 256 + t * 16 + r] = hh;
        Nl[tile * 256 + t * 16 + r] = ll;
    }
    {
        const int c = tid >> 1, t0e = (tid & 1) * 8;
        const int g = c >> 4;
        float vals[8];
#pragma unroll
        for (int j = 0; j < 8; ++j) vals[j] = kt2[c][t0e + j] * fctl[t0e + j][g];
        bf16x8 hi, lo;
        split8arr(vals, hi, lo);
        *(bf16x8*)(Kdh + tile * 2048 + c * 16 + t0e) = hi;
        *(bf16x8*)(Kdl + tile * 2048 + c * 16 + t0e) = lo;
    }
}

// ---------------------------------------------------------------------------
// Serial chunked recurrence, v3 (verified round 21/23 best): single barrier
// per chunk, double-buffered vb/scr, full register prefetch of next-chunk
// operands. 256 blocks.
// ---------------------------------------------------------------------------
__launch_bounds__(256)
__global__ void chunk_recur(const float* __restrict__ qt_g, const float* __restrict__ kt_g,
                            const float* __restrict__ vt_g,
                            const unsigned short* __restrict__ Nh, const unsigned short* __restrict__ Nl,
                            const unsigned short* __restrict__ Aqh, const unsigned short* __restrict__ Aql,
                            const unsigned short* __restrict__ Kdh, const unsigned short* __restrict__ Kdl,
                            const float* __restrict__ wexpg, float* __restrict__ o) {
    __shared__ float Sl[128][17];
    __shared__ float scr0[2][4][16][17];
    __shared__ float scr1[2][4][16][17];
    __shared__ float vb[2][16][17];
    __shared__ float xb4[4][16][17];
    __shared__ float dl4[4][16][17];

    const int bid = blockIdx.x;
    const int xcd = bid & 7, rr = bid >> 3;
    const int bh = xcd * 4 + (rr >> 3);
    const int slice = rr & 7;
    const int b = bh >> 4, h = bh & 15;
    const int tid = threadIdx.x;
    const int w = tid >> 6, lane = tid & 63, l15 = lane & 15, lk = lane >> 4;
    const size_t kbase = (size_t)bh * 131072;
    const size_t obase = ((size_t)b * 1024 * 16 + h) * 128;
    const int cq = w * 32 + lk * 8;
    const int gq2 = cq >> 4;
    const int tv = tid >> 4, u = tid & 15;

    for (int i = tid; i < 128 * 17; i += 256) ((float*)Sl)[i] = 0.f;
    __syncthreads();

    // prefetch ALL operands for chunk 0
    float kr[8], qr[8], vr, ex;
    bf16x8 nhR = zero8(), nlR = zero8(), ahR = zero8(), alR = zero8();
    bf16x8 kdh0 = zero8(), kdl0 = zero8(), kdh1 = zero8(), kdl1 = zero8();
    float w16R0, w16R1;
    {
        const size_t tile0 = (size_t)(bh * 64);
        const size_t rb = kbase + (size_t)(l15 >> 3) * 1024 + (size_t)(l15 & 7);
#pragma unroll
        for (int j = 0; j < 8; ++j) {
            kr[j] = kt_g[rb + (size_t)(cq + j) * 8];
            qr[j] = qt_g[rb + (size_t)(cq + j) * 8];
        }
        vr = vt_g[kbase + (size_t)(tv >> 3) * 1024 + (size_t)(slice * 16 + u) * 8 + (tv & 7)];
        ex = wexpg[tile0 * 128 + l15 * 8 + gq2];
        if (lk < 2) {
            nhR = *(const bf16x8*)(Nh + tile0 * 256 + l15 * 16 + lk * 8);
            nlR = *(const bf16x8*)(Nl + tile0 * 256 + l15 * 16 + lk * 8);
            ahR = *(const bf16x8*)(Aqh + tile0 * 256 + l15 * 16 + lk * 8);
            alR = *(const bf16x8*)(Aql + tile0 * 256 + l15 * 16 + lk * 8);
            kdh0 = *(const bf16x8*)(Kdh + tile0 * 2048 + (size_t)((w * 2 + 0) * 16 + l15) * 16 + lk * 8);
            kdl0 = *(const bf16x8*)(Kdl + tile0 * 2048 + (size_t)((w * 2 + 0) * 16 + l15) * 16 + lk * 8);
            kdh1 = *(const bf16x8*)(Kdh + tile0 * 2048 + (size_t)((w * 2 + 1) * 16 + l15) * 16 + lk * 8);
            kdl1 = *(const bf16x8*)(Kdl + tile0 * 2048 + (size_t)((w * 2 + 1) * 16 + l15) * 16 + lk * 8);
        }
        w16R0 = wexpg[tile0 * 128 + 120 + w * 2 + 0];
        w16R1 = wexpg[tile0 * 128 + 120 + w * 2 + 1];
    }

    for (int ch = 0; ch < 64; ++ch) {
        const int cur = ch & 1;
        const int cn = (ch + 1 < 64) ? (ch + 1) : ch;
        const size_t tilen = (size_t)(bh * 64 + cn);

        // stage v for current chunk (double-buffered)
        vb[cur][tv][u] = vr;

        // ---- phase A: E0/Oq partials from registers ----
        {
            float kv[8], qv[8], sv[8];
#pragma unroll
            for (int j = 0; j < 8; ++j) {
                kv[j] = kr[j] * ex;
                qv[j] = qr[j] * ex;
                sv[j] = Sl[cq + j][l15];
            }
            bf16x8 wh, wl, qh, ql, sh, sl2;
            split8arr(kv, wh, wl);
            split8arr(qv, qh, ql);
            split8arr(sv, sh, sl2);
            f32x4 e0 = (f32x4){0.f, 0.f, 0.f, 0.f};
            f32x4 oq = (f32x4){0.f, 0.f, 0.f, 0.f};
            e0 = MFMA16(wh, sh, e0); e0 = MFMA16(wh, sl2, e0); e0 = MFMA16(wl, sh, e0);
            oq = MFMA16(qh, sh, oq); oq = MFMA16(qh, sl2, oq); oq = MFMA16(ql, sh, oq);
#pragma unroll
            for (int j = 0; j < 4; ++j) {
                scr0[cur][w][lk * 4 + j][l15] = e0[j];
                scr1[cur][w][lk * 4 + j][l15] = oq[j];
            }
        }

        // ---- prefetch next chunk k/q/v/ex (clamped) ----
        {
            const size_t gb2 = kbase + (size_t)(cn * 2) * 1024;
            const size_t rb2 = gb2 + (size_t)(l15 >> 3) * 1024 + (size_t)(l15 & 7);
#pragma unroll
            for (int j = 0; j < 8; ++j) {
                kr[j] = kt_g[rb2 + (size_t)(cq + j) * 8];
                qr[j] = qt_g[rb2 + (size_t)(cq + j) * 8];
            }
            vr = vt_g[gb2 + (size_t)(tv >> 3) * 1024 + (size_t)(slice * 16 + u) * 8 + (tv & 7)];
            ex = wexpg[tilen * 128 + l15 * 8 + gq2];
        }

        __syncthreads();   // the ONLY barrier per chunk

        // ---- phase B (all waves redundant): x = v - sum(E0); d = N@x ----
        bf16x8 dh2, dl2;
        {
            const int tt = lane >> 2, v0 = (lane & 3) * 4;
#pragma unroll
            for (int uu = 0; uu < 4; ++uu) {
                const int v = v0 + uu;
                xb4[w][tt][v] = vb[cur][tt][v] -
                    (scr0[cur][0][tt][v] + scr0[cur][1][tt][v] +
                     scr0[cur][2][tt][v] + scr0[cur][3][tt][v]);
            }
            float xv[8];
            if (lk < 2) {
#pragma unroll
                for (int j = 0; j < 8; ++j) xv[j] = xb4[w][lk * 8 + j][l15];
            } else {
#pragma unroll
                for (int j = 0; j < 8; ++j) xv[j] = 0.f;
            }
            bf16x8 xh, xl;
            split8arr(xv, xh, xl);
            f32x4 d = (f32x4){0.f, 0.f, 0.f, 0.f};
            d = MFMA16(nhR, xh, d); d = MFMA16(nhR, xl, d); d = MFMA16(nlR, xh, d);
#pragma unroll
            for (int j = 0; j < 4; ++j) dl4[w][lk * 4 + j][l15] = d[j];

            float dv[8];
            if (lk < 2) {
#pragma unroll
                for (int j = 0; j < 8; ++j) dv[j] = dl4[w][lk * 8 + j][l15];
            } else {
#pragma unroll
                for (int j = 0; j < 8; ++j) dv[j] = 0.f;
            }
            split8arr(dv, dh2, dl2);

            // o output (wave 0 only)
            if (w == 0) {
                f32x4 oc;
#pragma unroll
                for (int j = 0; j < 4; ++j) {
                    const int t = lk * 4 + j;
                    oc[j] = scr1[cur][0][t][l15] + scr1[cur][1][t][l15] +
                            scr1[cur][2][t][l15] + scr1[cur][3][t][l15];
                }
                oc = MFMA16(ahR, dh2, oc); oc = MFMA16(ahR, dl2, oc); oc = MFMA16(alR, dh2, oc);
#pragma unroll
                for (int j = 0; j < 4; ++j)
                    o[obase + (size_t)(ch * 16 + lk * 4 + j) * 2048 + slice * 16 + l15] = oc[j];
            }
        }

        // ---- prefetch next N/Aq (consumed; safe to overwrite) ----
        if (lk < 2) {
            nhR = *(const bf16x8*)(Nh + tilen * 256 + l15 * 16 + lk * 8);
            nlR = *(const bf16x8*)(Nl + tilen * 256 + l15 * 16 + lk * 8);
            ahR = *(const bf16x8*)(Aqh + tilen * 256 + l15 * 16 + lk * 8);
            alR = *(const bf16x8*)(Aql + tilen * 256 + l15 * 16 + lk * 8);
        }

        // ---- phase C: S update (own rows; operands in registers) ----
        {
            f32x4 sc;
#pragma unroll
            for (int j = 0; j < 4; ++j) sc[j] = Sl[(w * 2 + 0) * 16 + lk * 4 + j][l15] * w16R0;
            sc = MFMA16(kdh0, dh2, sc); sc = MFMA16(kdh0, dl2, sc); sc = MFMA16(kdl0, dh2, sc);
#pragma unroll
            for (int j = 0; j < 4; ++j) Sl[(w * 2 + 0) * 16 + lk * 4 + j][l15] = sc[j];

            f32x4 sc1;
#pragma unroll
            for (int j = 0; j < 4; ++j) sc1[j] = Sl[(w * 2 + 1) * 16 + lk * 4 + j][l15] * w16R1;
            sc1 = MFMA16(kdh1, dh2, sc1); sc1 = MFMA16(kdh1, dl2, sc1); sc1 = MFMA16(kdl1, dh2, sc1);
#pragma unroll
            for (int j = 0; j < 4; ++j) Sl[(w * 2 + 1) * 16 + lk * 4 + j][l15] = sc1[j];
        }

        // ---- prefetch next Kd/w16 (consumed; safe to overwrite) ----
        if (lk < 2) {
            kdh0 = *(const bf16x8*)(Kdh + tilen * 2048 + (size_t)((w * 2 + 0) * 16 + l15) * 16 + lk * 8);
            kdl0 = *(const bf16x8*)(Kdl + tilen * 2048 + (size_t)((w * 2 + 0) * 16 + l15) * 16 + lk * 8);
            kdh1 = *(const bf16x8*)(Kdh + tilen * 2048 + (size_t)((w * 2 + 1) * 16 + l15) * 16 + lk * 8);
            kdl1 = *(const bf16x8*)(Kdl + tilen * 2048 + (size_t)((w * 2 + 1) * 16 + l15) * 16 + lk * 8);
        }
        w16R0 = wexpg[tilen * 128 + 120 + w * 2 + 0];
        w16R1 = wexpg[tilen * 128 + 120 + w * 2 + 1];
    }
}

// ---------------------------------------------------------------------------
// Old-layout recurrence (fallback path only).
// ---------------------------------------------------------------------------
__launch_bounds__(256, 4)
__global__ void recur_kernel(const float* __restrict__ q, const float* __restrict__ k,
                             const float* __restrict__ vv, const float* __restrict__ decay,
                             const float* __restrict__ beta, float* __restrict__ o) {
    const int blk = blockIdx.x;
    const int vblk = blk & 31;
    const int bh = blk >> 5;
    const int b = bh >> 4, h = bh & 15;
    const int w = threadIdx.x >> 6;
    const int lane = threadIdx.x & 63;
    const int vi = vblk * 4 + w;

    float S0 = 0.f, S1 = 0.f;
    const size_t strideT = (size_t)HH * DV;
    const size_t strideT2 = strideT >> 1;
    const size_t base = ((size_t)b * TT * HH + h) * DV;

    const float2* kp = (const float2*)(k + base) + lane;
    const float2* qp = (const float2*)(q + base) + lane;
    const float* vp = vv + base + vi;
    const float* bp = beta + (size_t)b * TT * HH + h;
    const float* dp = decay + ((size_t)b * TT * HH + h) * NG + (lane >> 3);

    float2 kv = kp[0], qv = qp[0];
    float vtv = vp[0], bt = bp[0], dt = dp[0];

    for (int t = 0; t < TT; ++t) {
        const float2 kc = kv, qc = qv;
        const float vc = vtv, bc = bt, dc = dt;

        const int tn = (t + 1 < TT) ? (t + 1) : t;
        kv = kp[(size_t)tn * strideT2];
        qv = qp[(size_t)tn * strideT2];
        vtv = vp[(size_t)tn * strideT];
        bt = bp[(size_t)tn * HH];
        dt = dp[(size_t)tn * HH * NG];

        S0 *= dc;
        S1 *= dc;
        float e = fmaf(kc.x, S0, kc.y * S1);
        e = dpp_sum64(e);
        const float err = readlanef(e, 63);
        const float delta = bc * (vc - err);
        S0 = fmaf(kc.x, delta, S0);
        S1 = fmaf(kc.y, delta, S1);
        float oo = fmaf(qc.x, S0, qc.y * S1);
        oo = dpp_sum64(oo);
        if (lane == 63) o[base + (size_t)t * strideT + vi] = oo;
    }
}

// ---------------------------------------------------------------------------
// Gated RMSNorm -> fp32 y (fallback)
// ---------------------------------------------------------------------------
__global__ void gated_rmsnorm(const float* __restrict__ o,
                              const float* __restrict__ gpre, const float* __restrict__ bg,
                              const float* __restrict__ norm_w, float* __restrict__ y) {
    const int blk = blockIdx.x;
    const int h = blk & 15;
    const int dv = threadIdx.x;
    const size_t off = (size_t)blk * DV + dv;

    const float ov = o[off];
    const float g = gpre[off] + bg[h * 128 + dv];
    const float yv = ov * (g / (1.f + expf(-g)));

    float ss = yv * yv;
#pragma unroll
    for (int s = 1; s < 64; s <<= 1) ss += __shfl_xor(ss, s, 64);
    __shared__ float red[2];
    if ((threadIdx.x & 63) == 0) red[threadIdx.x >> 6] = ss;
    __syncthreads();
    const float mean = (red[0] + red[1]) * (1.f / 128.f);
    y[off] = yv * rsqrtf(mean + 1e-5f) * norm_w[dv];
}

// ---------------------------------------------------------------------------
// Gated RMSNorm -> bf16 hi/lo split y
// ---------------------------------------------------------------------------
__global__ void gated_rmsnorm_split(const float* __restrict__ o,
                                    const float* __restrict__ gpre, const float* __restrict__ bg,
                                    const float* __restrict__ norm_w,
                                    unsigned short* __restrict__ yh,
                                    unsigned short* __restrict__ yl) {
    const int blk = blockIdx.x;
    const int h = blk & 15;
    const int dv = threadIdx.x;
    const size_t off = (size_t)blk * DV + dv;

    const float ov = o[off];
    const float g = gpre[off] + bg[h * 128 + dv];
    const float yv = ov * (g / (1.f + expf(-g)));

    float ss = yv * yv;
#pragma unroll
    for (int s = 1; s < 64; s <<= 1) ss += __shfl_xor(ss, s, 64);
    __shared__ float red[2];
    if ((threadIdx.x & 63) == 0) red[threadIdx.x >> 6] = ss;
    __syncthreads();
    const float mean = (red[0] + red[1]) * (1.f / 128.f);
    const float y = yv * rsqrtf(mean + 1e-5f) * norm_w[dv];
    unsigned short hh, ll;
    bsplit(y, hh, ll);
    yh[off] = hh;
    yl[off] = ll;
}

// ---------------------------------------------------------------------------
extern "C" void kernel_launch(void* const* d_in, const int* in_sizes, int n_in,
                              void* d_out, int out_size, void* d_ws, size_t ws_size,
                              hipStream_t stream) {
    const float* hid    = (const float*)d_in[0];
    const float* Wq     = (const float*)d_in[1];
    const float* Wk     = (const float*)d_in[2];
    const float* Wv     = (const float*)d_in[3];
    const float* conv_q = (const float*)d_in[4];
    const float* conv_k = (const float*)d_in[5];
    const float* conv_v = (const float*)d_in[6];
    const float* Wf1    = (const float*)d_in[7];
    const float* Wf2    = (const float*)d_in[8];
    const float* Wb     = (const float*)d_in[9];
    const float* A_log  = (const float*)d_in[10];
    const float* dt_bias= (const float*)d_in[11];
    const float* Wg     = (const float*)d_in[12];
    const float* bg     = (const float*)d_in[13];
    const float* norm_w = (const float*)d_in[14];
    const float* Wo     = (const float*)d_in[15];
    float* out = (float*)d_out;

    const size_t N1  = (size_t)2048 * 2048;
    const size_t N1B = N1 * 4;
    const int M = BB * TT;

    const size_t NEED_NEW = 9 * N1B + 4390912;

    if (ws_size >= NEED_NEW) {
        // ---------------- MFMA split-precision path ----------------
        // Region map (all aliases verified against launch order):
        //  W  [0,16M):  hidh/hidl (dead after input GEMMs) -> o
        //  RB [16,80M): Wq/Wk/Wv/Wg transposes (dead after GEMMs) ->
        //               qn_t / kn_t / vn_t (tiled conv out) ; yh/yl over Wg
        //  RC [80,144M): qpre..gpre ; after conv_tile3: N/Aq/wexpg over qpre,
        //               Kd over kpre, Woth/Wotl over vpre; gpre persists
        //  RD tail: g1b/g2b/beta/ldec/wf1 transposes
        char* W = (char*)d_ws;
        unsigned short* hidh = (unsigned short*)W;
        unsigned short* hidl = hidh + N1;
        float* o = (float*)W;
        char* RB = W + N1B;
        unsigned short* Wqth = (unsigned short*)RB;
        unsigned short* Wqtl = Wqth + N1;
        unsigned short* Wkth = Wqtl + N1;
        unsigned short* Wktl = Wkth + N1;
        unsigned short* Wvth = Wktl + N1;
        unsigned short* Wvtl = Wvth + N1;
        unsigned short* Wgth = Wvtl + N1;
        unsigned short* Wgtl = Wgth + N1;
        float* qn_t = (float*)RB;
        float* kn_t = (float*)(RB + N1B);
        float* vn_t = (float*)(RB + 2 * N1B);
        unsigned short* yh = (unsigned short*)(RB + 3 * N1B);
        unsigned short* yl = yh + N1;
        char* RC = W + 5 * N1B;
        float* qpre = (float*)RC;
        float* kpre = qpre + N1;
        float* vpre = kpre + N1;
        float* gpre = vpre + N1;
        unsigned short* Nh  = (unsigned short*)RC;
        unsigned short* Nl  = Nh + 524288;
        unsigned short* Aqh = Nl + 524288;
        unsigned short* Aql = Aqh + 524288;
        float* wexpg = (float*)(Aql + 524288);
        unsigned short* Kdh = (unsigned short*)(RC + N1B);
        unsigned short* Kdl = Kdh + 4194304;
        unsigned short* Woth = (unsigned short*)(RC + 2 * N1B);
        unsigned short* Wotl = Woth + N1;
        char* RD = W + 9 * N1B;
        float* g1b   = (float*)RD;
        float* g2b   = g1b + 262144;
        float* betab = g2b + 262144;
        float* ldecb = betab + 32768;
        unsigned short* wf1th = (unsigned short*)(ldecb + 262144);
        unsigned short* wf1tl = wf1th + 262144;

        // 1. splits / transposes
        split_mat<<<1024, 256, 0, stream>>>(hid, hidh, hidl);
        TS4 ts;
        ts.in[0] = Wq; ts.oh[0] = Wqth; ts.ol[0] = Wqtl;
        ts.in[1] = Wk; ts.oh[1] = Wkth; ts.ol[1] = Wktl;
        ts.in[2] = Wv; ts.oh[2] = Wvth; ts.ol[2] = Wvtl;
        ts.in[3] = Wg; ts.oh[3] = Wgth; ts.ol[3] = Wgtl;
        transpose_split4<<<dim3(32, 32, 4), 256, 0, stream>>>(ts);
        transpose_split<<<dim3(2, 32), 256, 0, stream>>>(Wf1, wf1th, wf1tl, 128, 2048);

        // 2. input projections: q/k/v/g PURE BF16 (NM=1, mode 1, grid 64x16),
        //    Wf1 split-3 (NM=3, mode 2, grid 1x16).
        GemmArgs fa;
        fa.Ah = hidh; fa.Al = hidl;
        fa.Bh[0] = Wqth; fa.Bl[0] = Wqtl; fa.C[0] = qpre;
        fa.Bh[1] = Wkth; fa.Bl[1] = Wktl; fa.C[1] = kpre;
        fa.Bh[2] = Wvth; fa.Bl[2] = Wvtl; fa.C[2] = vpre;
        fa.Bh[3] = Wgth; fa.Bl[3] = Wgtl; fa.C[3] = gpre;
        fa.Bh[4] = wf1th; fa.Bl[4] = wf1tl; fa.C[4] = g1b;
        gemm_split<1><<<dim3(64, 16), 256, 0, stream>>>(fa, 1);
        gemm_split<3><<<dim3(1, 16), 256, 0, stream>>>(fa, 2);

        // 3. beta, g2, log-decay (t-tiled)
        beta_kernel<<<M, 256, 0, stream>>>(hid, Wb, betab);
        sgemm128<<<dim3(1, 16), 256, 0, stream>>>(g1b, Wf2, g2b, M, 128, 128);
        ldecay_kernel_t<<<(M * HH * NG) / 256, 256, 0, stream>>>(g2b, A_log, dt_bias, ldecb);

        // 4. fused conv + silu (+l2norm) -> t-tiled outputs (over dead W transposes)
        CT3 ct;
        ct.pre[0] = qpre; ct.w[0] = conv_q; ct.out[0] = qn_t; ct.scale[0] = SCALE_Q; ct.do_norm[0] = 1;
        ct.pre[1] = kpre; ct.w[1] = conv_k; ct.out[1] = kn_t; ct.scale[1] = 1.f;     ct.do_norm[1] = 1;
        ct.pre[2] = vpre; ct.w[2] = conv_v; ct.out[2] = vn_t; ct.scale[2] = 1.f;     ct.do_norm[2] = 0;
        conv_tile3<<<dim3(4096, 3), 128, 0, stream>>>(ct);

        // 5. prep (parallel; writes N over dead qpre, Kd over dead kpre)
        prep_kernel<<<2048, 256, 0, stream>>>(kn_t, qn_t, ldecb, betab,
                                              Nh, Nl, Aqh, Aql, Kdh, Kdl, wexpg);
        // 6. serial chunked recurrence (writes o over dead hidh/hidl)
        chunk_recur<<<256, 256, 0, stream>>>(qn_t, kn_t, vn_t,
                                             Nh, Nl, Aqh, Aql, Kdh, Kdl, wexpg, o);

        // 7. transpose Wo (over dead vpre)
        transpose_split<<<dim3(32, 32), 256, 0, stream>>>(Wo, Woth, Wotl, 2048, 2048);

        // 8. gated rmsnorm -> y split (over dead Wg transposes)
        gated_rmsnorm_split<<<M * HH, 128, 0, stream>>>(o, gpre, bg, norm_w, yh, yl);

        // 9. output projection (split-2, NM=2, mode 0)
        GemmArgs oa;
        oa.Ah = yh; oa.Al = yl;
        for (int i = 0; i < 5; ++i) { oa.Bh[i] = Woth; oa.Bl[i] = Wotl; oa.C[i] = out; }
        gemm_split<2><<<dim3(16, 16), 256, 0, stream>>>(oa, 0);
    } else {
        // ---------------- fallback: fp32 path ----------------
        float* ws = (float*)d_ws;
        float* qpre = ws + 0 * N1;
        float* kpre = ws + 1 * N1;
        float* vpre = ws + 2 * N1;
        float* gpre = ws + 3 * N1;
        float* qn   = ws + 4 * N1;
        float* kn   = ws + 5 * N1;
        float* vn   = ws + 6 * N1;
        float* g1b  = ws + 7 * N1;
        float* g2b  = g1b + (size_t)BB * TT * DV;
        float* betab= g2b + (size_t)BB * TT * HH * NG;
        float* decayb = betab + (size_t)BB * TT * HH;
        float* o = qpre;
        float* y = vpre;

        sgemm128<<<dim3(16, 16), 256, 0, stream>>>(hid, Wq, qpre, M, 2048, 2048);
        sgemm128<<<dim3(16, 16), 256, 0, stream>>>(hid, Wk, kpre, M, 2048, 2048);
        sgemm128<<<dim3(16, 16), 256, 0, stream>>>(hid, Wv, vpre, M, 2048, 2048);
        sgemm128<<<dim3(16, 16), 256, 0, stream>>>(hid, Wg, gpre, M, 2048, 2048);
        sgemm128<<<dim3(1, 16), 256, 0, stream>>>(hid, Wf1, g1b, M, 128, 2048);
        sgemm128<<<dim3(1, 16), 256, 0, stream>>>(g1b, Wf2, g2b, M, 128, 128);
        beta_kernel<<<M, 256, 0, stream>>>(hid, Wb, betab);

        conv_silu_norm<<<M * HH, 128, 0, stream>>>(qpre, conv_q, qn, SCALE_Q, 1);
        conv_silu_norm<<<M * HH, 128, 0, stream>>>(kpre, conv_k, kn, 1.f, 1);
        conv_silu_norm<<<M * HH, 128, 0, stream>>>(vpre, conv_v, vn, 1.f, 0);

        decay_kernel<<<(M * HH * NG) / 256, 256, 0, stream>>>(g2b, A_log, dt_bias, decayb);

        recur_kernel<<<BB * HH * (DV / 4), 256, 0, stream>>>(qn, kn, vn, decayb, betab, o);

        gated_rmsnorm<<<M * HH, 128, 0, stream>>>(o, gpre, bg, norm_w, y);

        sgemm128<<<dim3(16, 16), 256, 0, stream>>>(y, Wo, out, M, 2048, 2048);
    }
}